// Round 6
// baseline (1936.545 us; speedup 1.0000x reference)
//
#include <hip/hip_runtime.h>
#include <hip/hip_cooperative_groups.h>
#include <math.h>

namespace cg = cooperative_groups;

// Shapes (fixed by the problem)
#define NBATCH 128
#define NPTS   196     // 14*14 patches
#define DIN    768     // 3*16*16
#define DM     384
#define KCL    16
#define NEXP   8
#define NITER  10
#define NCLS   1000

// ---------------------------------------------------------------------------
// K0: init out = cb (classifier bias), zero the merge mask
// ---------------------------------------------------------------------------
__global__ __launch_bounds__(256) void init_kernel(const float* __restrict__ cb,
                                                   float* __restrict__ out,
                                                   int* __restrict__ mask) {
    int idx = blockIdx.x * 256 + threadIdx.x;
    if (idx < NBATCH * NCLS) {
        out[idx] = cb[idx % NCLS];
    } else if (idx < NBATCH * NCLS + 256) {
        mask[idx - NBATCH * NCLS] = 0;
    }
}

// ---------------------------------------------------------------------------
// K1: patch extraction + GEMM (25088x768 @ 768x384) + bias + LayerNorm + pnsq
// 256 threads, BM=64, BK=16, micro 8x12 (b128 LDS reads, conflict-free:
// quad index 3*cg mod 8 is a bijection). Ping-pong LDS double-buffer +
// register prefetch: ONE barrier per k-block, global latency hidden.
// ---------------------------------------------------------------------------
#define BKP 16
__global__ __launch_bounds__(256) void patch_ln_kernel(
        const float* __restrict__ x, const float* __restrict__ pw,
        const float* __restrict__ pb, const float* __restrict__ lng,
        const float* __restrict__ lnb, float* __restrict__ pn,
        float* __restrict__ pnsq) {
    __shared__ float As[2][BKP * 68];   // [kk][row], 64 rows + 4 pad
    __shared__ float Ws[2][BKP * DM];   // [kk][col]
    const int tid = threadIdx.x;
    const int m0  = blockIdx.x * 64;
    const int rg  = tid >> 5, cg = tid & 31;   // 8 row-groups x 32 col-groups
    // A-stage mapping: 64 loader rows x 4 k-quads
    const int lr = tid >> 2, kq = tid & 3;
    const int m  = m0 + lr;
    const int bi = m / NPTS, n = m - bi * NPTS;
    const int nh = n / 14, nwp = n - nh * 14;
    const float* xb = x + (size_t)bi * 150528 + (size_t)(nh * 16) * 224 + nwp * 16;

    float acc[8][12];
#pragma unroll
    for (int r = 0; r < 8; ++r)
#pragma unroll
        for (int j = 0; j < 12; ++j) acc[r][j] = 0.f;

    const float4* pw4 = (const float4*)pw;

    // prefetch k-block 0 into registers
    float4 xa;
    float4 wv[6];
    {
        int k = kq * 4;
        int c = k >> 8, py = (k >> 4) & 15, px = k & 15;
        xa = *(const float4*)(xb + c * 50176 + py * 224 + px);
#pragma unroll
        for (int t = 0; t < 6; ++t) wv[t] = pw4[tid + t * 256];
    }

    int p = 0;
    for (int kcb = 0; kcb < 48; ++kcb) {
        // write staged registers into LDS buffer p
        As[p][(kq * 4 + 0) * 68 + lr] = xa.x;
        As[p][(kq * 4 + 1) * 68 + lr] = xa.y;
        As[p][(kq * 4 + 2) * 68 + lr] = xa.z;
        As[p][(kq * 4 + 3) * 68 + lr] = xa.w;
#pragma unroll
        for (int t = 0; t < 6; ++t) ((float4*)Ws[p])[tid + t * 256] = wv[t];
        __syncthreads();
        // prefetch next k-block (consumed ~3000 cycles later)
        if (kcb + 1 < 48) {
            int k = (kcb + 1) * BKP + kq * 4;
            int c = k >> 8, py = (k >> 4) & 15, px = k & 15;
            xa = *(const float4*)(xb + c * 50176 + py * 224 + px);
#pragma unroll
            for (int t = 0; t < 6; ++t)
                wv[t] = pw4[(kcb + 1) * 1536 + tid + t * 256];
        }
        // compute from buffer p
#pragma unroll 4
        for (int kk = 0; kk < BKP; ++kk) {
            float a[8];
            *(float4*)&a[0] = *(const float4*)&As[p][kk * 68 + rg * 8];
            *(float4*)&a[4] = *(const float4*)&As[p][kk * 68 + rg * 8 + 4];
            float w[12];
            *(float4*)&w[0] = *(const float4*)&Ws[p][kk * DM + cg * 12];
            *(float4*)&w[4] = *(const float4*)&Ws[p][kk * DM + cg * 12 + 4];
            *(float4*)&w[8] = *(const float4*)&Ws[p][kk * DM + cg * 12 + 8];
#pragma unroll
            for (int r = 0; r < 8; ++r)
#pragma unroll
                for (int j = 0; j < 12; ++j) acc[r][j] += a[r] * w[j];
        }
        p ^= 1;
    }

    // epilogue: +bias, LayerNorm (two-pass), write pn and pnsq
    float gvv[12], bvv[12], pbv[12];
#pragma unroll
    for (int j4 = 0; j4 < 3; ++j4) {
        *(float4*)&pbv[j4 * 4] = *(const float4*)(pb + cg * 12 + j4 * 4);
        *(float4*)&gvv[j4 * 4] = *(const float4*)(lng + cg * 12 + j4 * 4);
        *(float4*)&bvv[j4 * 4] = *(const float4*)(lnb + cg * 12 + j4 * 4);
    }
#pragma unroll
    for (int r = 0; r < 8; ++r) {
        float vloc[12];
        float s = 0.f;
#pragma unroll
        for (int j = 0; j < 12; ++j) { vloc[j] = acc[r][j] + pbv[j]; s += vloc[j]; }
#pragma unroll
        for (int off = 16; off >= 1; off >>= 1) s += __shfl_xor(s, off);
        float mu = s * (1.0f / DM);
        float q = 0.f;
#pragma unroll
        for (int j = 0; j < 12; ++j) { float dd = vloc[j] - mu; q += dd * dd; }
#pragma unroll
        for (int off = 16; off >= 1; off >>= 1) q += __shfl_xor(q, off);
        float rstd = rsqrtf(q * (1.0f / DM) + 1e-5f);
        float ov[12];
        float ssq = 0.f;
#pragma unroll
        for (int j = 0; j < 12; ++j) {
            float pv = (vloc[j] - mu) * rstd * gvv[j] + bvv[j];
            ov[j] = pv; ssq += pv * pv;
        }
#pragma unroll
        for (int off = 16; off >= 1; off >>= 1) ssq += __shfl_xor(ssq, off);
        int mr = m0 + rg * 8 + r;
        float* dst = pn + (size_t)mr * DM + cg * 12;
        *(float4*)(dst)     = *(float4*)&ov[0];
        *(float4*)(dst + 4) = *(float4*)&ov[4];
        *(float4*)(dst + 8) = *(float4*)&ov[8];
        if (cg == 0) pnsq[mr] = ssq;
    }
}

// ---------------------------------------------------------------------------
// K2: FULL k-means in ONE cooperative kernel. grid (2 halves x 128 batches) =
// 256 blocks (1/CU, co-resident). Centers live in LDS for all 10 iters.
// Per iter: assign own 98 points (proven sub-lane-8 pattern, identical
// numerics) -> ballot masks -> per-half partial sums (ascending point order,
// deterministic) -> grid.sync -> both blocks reduce halves, divide, csq ->
// grid.sync. Finally write c0 = cent + pos (split by half).
// ---------------------------------------------------------------------------
__global__ __launch_bounds__(256) void kmeans_coop_kernel(
        const float* __restrict__ pn, const float* __restrict__ pnsq,
        const float* __restrict__ pos, float* __restrict__ gsums,
        int* __restrict__ gcnt, float* __restrict__ c0) {
    cg::grid_group grid = cg::this_grid();
    __shared__ float cs[KCL * DM];            // 24 KB centers
    __shared__ float cq[KCL];
    __shared__ unsigned long long mskS[KCL * 2];
    __shared__ int tcnt[KCL];
    __shared__ int cntS[KCL];
    const int h = blockIdx.x, b = blockIdx.y, tid = threadIdx.x;
    const float4* pn4 = (const float4*)(pn + (size_t)b * NPTS * DM);
    float4* cs4 = (float4*)cs;

    // init centers = pn[13k]
    for (int i = tid; i < KCL * 96; i += 256) {
        int k = i / 96, d4 = i - k * 96;
        cs4[i] = pn4[(size_t)(13 * k) * 96 + d4];
    }
    __syncthreads();
    {   // initial csq
        int k = tid >> 4, su = tid & 15;
        float ss = 0.f;
        for (int t = 0; t < 24; ++t) { float v = cs[k * DM + su + 16 * t]; ss += v * v; }
#pragma unroll
        for (int off = 8; off >= 1; off >>= 1) ss += __shfl_xor(ss, off);
        if (su == 0) cq[k] = ss;
    }
    __syncthreads();

    const int sub = tid & 7, pg = tid >> 3;   // 32 point-groups x 8 sub-lanes

    for (int it = 0; it < NITER; ++it) {
        if (tid < KCL) tcnt[tid] = 0;
        if (tid < KCL * 2) mskS[tid] = 0ull;
        __syncthreads();

        // ---- phase 1: assign own 98 points ----
        for (int np = pg; np < 98; np += 32) {
            const int n = h * 98 + np;
            const float4* prow = (const float4*)(pn + ((size_t)b * NPTS + n) * DM);
            float acc[KCL];
#pragma unroll
            for (int k = 0; k < KCL; ++k) acc[k] = 0.f;
#pragma unroll 2
            for (int i = 0; i < 12; ++i) {
                const int d4 = sub + 8 * i;
                float4 pv = prow[d4];
#pragma unroll
                for (int k = 0; k < KCL; ++k) {
                    const float4 c = *(const float4*)&cs[k * DM + d4 * 4];
                    acc[k] += pv.x * c.x + pv.y * c.y + pv.z * c.z + pv.w * c.w;
                }
            }
#pragma unroll
            for (int k = 0; k < KCL; ++k) {
                float a = acc[k];
                a += __shfl_xor(a, 1);
                a += __shfl_xor(a, 2);
                a += __shfl_xor(a, 4);
                acc[k] = a;
            }
            if (sub == 0) {
                const float mp = pnsq[b * NPTS + n];
                float best = (mp - 2.0f * acc[0]) + cq[0];
                int bk = 0;
#pragma unroll
                for (int k = 1; k < KCL; ++k) {
                    float v = (mp - 2.0f * acc[k]) + cq[k];
                    if (v < best) { best = v; bk = k; }  // strict <: first min
                }
                atomicAdd(&tcnt[bk], 1);
                atomicOr(&mskS[bk * 2 + (np >> 6)], 1ull << (np & 63));
            }
        }
        __syncthreads();

        // ---- phase 2: per-half partial sums (ascending order) ----
        if (tid < 192) {
            const int c2 = 2 * tid;
            const float* base = pn + ((size_t)b * NPTS + h * 98) * DM + c2;
            float* dsts = gsums + ((size_t)(b * 2 + h) * KCL) * DM + c2;
#pragma unroll
            for (int k = 0; k < KCL; ++k) {
                float sx = 0.f, sy = 0.f;
#pragma unroll
                for (int w = 0; w < 2; ++w) {
                    unsigned long long mm = mskS[k * 2 + w];
                    while (mm) {
                        int pp = w * 64 + (int)__builtin_ctzll(mm);
                        mm &= mm - 1;
                        float2 v = *(const float2*)(base + (size_t)pp * DM);
                        sx += v.x; sy += v.y;
                    }
                }
                *(float2*)(dsts + (size_t)k * DM) = make_float2(sx, sy);
            }
        }
        if (tid < KCL) gcnt[(b * 2 + h) * KCL + tid] = tcnt[tid];
        grid.sync();

        // ---- phase 3: both blocks reduce the two halves redundantly ----
        if (tid < KCL)
            cntS[tid] = gcnt[(b * 2) * KCL + tid] + gcnt[(b * 2 + 1) * KCL + tid];
        __syncthreads();
        const float4* G0 = (const float4*)(gsums + (size_t)(b * 2) * KCL * DM);
        const float4* G1 = G0 + KCL * 96;
        for (int i = tid; i < KCL * 96; i += 256) {
            int k = i / 96;
            float4 s0 = G0[i], s1 = G1[i];
            float4 s = make_float4(s0.x + s1.x, s0.y + s1.y, s0.z + s1.z, s0.w + s1.w);
            int c = cntS[k];
            float4 o;
            if (c > 0) {
                float inv = 1.0f / (float)c;
                o = make_float4(s.x * inv, s.y * inv, s.z * inv, s.w * inv);
            } else {
                o = cs4[i];
            }
            cs4[i] = o;
        }
        __syncthreads();
        {   // csq of new centers
            int k = tid >> 4, su = tid & 15;
            float ss = 0.f;
            for (int t = 0; t < 24; ++t) { float v = cs[k * DM + su + 16 * t]; ss += v * v; }
#pragma unroll
            for (int off = 8; off >= 1; off >>= 1) ss += __shfl_xor(ss, off);
            if (su == 0) cq[k] = ss;
        }
        grid.sync();   // gsums/gcnt consumed by all before next overwrite
    }

    // finalize: c0 = cent + pos, each block writes its half
    const float4* pos4 = (const float4*)pos;
    float4* c04 = (float4*)(c0 + (size_t)b * KCL * DM);
    for (int i = tid; i < 768; i += 256) {
        int ii = h * 768 + i;
        float4 cv = cs4[ii];
        float4 pv = pos4[ii];
        c04[ii] = make_float4(cv.x + pv.x, cv.y + pv.y, cv.z + pv.z, cv.w + pv.w);
    }
}

// ---------------------------------------------------------------------------
// K3: fused QKV GEMM: 3 outputs from one A-tile staging. BM=32, BN=128, BK=32.
// ---------------------------------------------------------------------------
__global__ __launch_bounds__(256) void gemm_qkv_kernel(
        const float* __restrict__ A,
        const float* __restrict__ qw, const float* __restrict__ kw,
        const float* __restrict__ vw,
        const float* __restrict__ qb, const float* __restrict__ kb,
        const float* __restrict__ vb,
        float* __restrict__ Q, float* __restrict__ K, float* __restrict__ V) {
    __shared__ float As[32 * 32];
    __shared__ float Ws[3][32 * 128];
    const int n0 = blockIdx.x * 128;
    const int m0 = blockIdx.y * 32;
    const int tid = threadIdx.x;
    const int rg = tid >> 5, cg = tid & 31;
    const int arow = tid >> 3, akg = tid & 7;
    const float* W[3] = {qw, kw, vw};

    float acc[3][4][4];
#pragma unroll
    for (int g = 0; g < 3; ++g)
#pragma unroll
        for (int r = 0; r < 4; ++r)
#pragma unroll
            for (int j = 0; j < 4; ++j) acc[g][r][j] = 0.f;

    for (int kc = 0; kc < DM; kc += 32) {
        float4 av = *(const float4*)(A + (size_t)(m0 + arow) * DM + kc + akg * 4);
        As[(akg * 4 + 0) * 32 + arow] = av.x;
        As[(akg * 4 + 1) * 32 + arow] = av.y;
        As[(akg * 4 + 2) * 32 + arow] = av.z;
        As[(akg * 4 + 3) * 32 + arow] = av.w;
#pragma unroll
        for (int g = 0; g < 3; ++g)
#pragma unroll
            for (int t = 0; t < 4; ++t) {
                int s = tid + t * 256;
                int kk = s >> 5, c4i = s & 31;
                *(float4*)&Ws[g][kk * 128 + c4i * 4] =
                    *(const float4*)(W[g] + (size_t)(kc + kk) * DM + n0 + c4i * 4);
            }
        __syncthreads();
#pragma unroll 8
        for (int kk = 0; kk < 32; ++kk) {
            float4 a = *(const float4*)&As[kk * 32 + rg * 4];
            float ar[4] = {a.x, a.y, a.z, a.w};
#pragma unroll
            for (int g = 0; g < 3; ++g) {
                float4 w = *(const float4*)&Ws[g][kk * 128 + cg * 4];
                float wr[4] = {w.x, w.y, w.z, w.w};
#pragma unroll
                for (int r = 0; r < 4; ++r)
#pragma unroll
                    for (int j = 0; j < 4; ++j) acc[g][r][j] += ar[r] * wr[j];
            }
        }
        __syncthreads();
    }
    const float* B[3] = {qb, kb, vb};
    float* O[3] = {Q, K, V};
#pragma unroll
    for (int g = 0; g < 3; ++g) {
        float4 bv = *(const float4*)(B[g] + n0 + cg * 4);
        float bvr[4] = {bv.x, bv.y, bv.z, bv.w};
#pragma unroll
        for (int r = 0; r < 4; ++r) {
            float o[4];
#pragma unroll
            for (int j = 0; j < 4; ++j) o[j] = acc[g][r][j] + bvr[j];
            *(float4*)(O[g] + (size_t)(m0 + rg * 4 + r) * DM + n0 + cg * 4) =
                *(float4*)&o[0];
        }
    }
}

// ---------------------------------------------------------------------------
// Generic fp32 GEMM: out(MxN) = A(MxK) @ W(KxN) + bias, optional exact GELU.
// ---------------------------------------------------------------------------
template <int ACT>
__global__ __launch_bounds__(256) void gemm_kernel(
        const float* __restrict__ A, const float* __restrict__ W,
        const float* __restrict__ bias, float* __restrict__ out,
        int M, int N, int Kd) {
    __shared__ float As[32 * 32];
    __shared__ float Ws[32 * 128];
    const int n0 = blockIdx.x * 128;
    const int m0 = blockIdx.y * 32;
    const int tid = threadIdx.x;
    const int rg = tid >> 5, cg = tid & 31;
    const int arow = tid >> 3, akg = tid & 7;
    float acc[4][4];
#pragma unroll
    for (int r = 0; r < 4; ++r)
#pragma unroll
        for (int j = 0; j < 4; ++j) acc[r][j] = 0.f;

    for (int kc = 0; kc < Kd; kc += 32) {
        float4 av = *(const float4*)(A + (size_t)(m0 + arow) * Kd + kc + akg * 4);
        As[(akg * 4 + 0) * 32 + arow] = av.x;
        As[(akg * 4 + 1) * 32 + arow] = av.y;
        As[(akg * 4 + 2) * 32 + arow] = av.z;
        As[(akg * 4 + 3) * 32 + arow] = av.w;
#pragma unroll
        for (int t = 0; t < 4; ++t) {
            int s = tid + t * 256;
            int kk = s >> 5, c4i = s & 31;
            *(float4*)&Ws[kk * 128 + c4i * 4] =
                *(const float4*)(W + (size_t)(kc + kk) * N + n0 + c4i * 4);
        }
        __syncthreads();
#pragma unroll 16
        for (int kk = 0; kk < 32; ++kk) {
            float4 a = *(const float4*)&As[kk * 32 + rg * 4];
            float4 w = *(const float4*)&Ws[kk * 128 + cg * 4];
            float ar[4] = {a.x, a.y, a.z, a.w};
            float wr[4] = {w.x, w.y, w.z, w.w};
#pragma unroll
            for (int r = 0; r < 4; ++r)
#pragma unroll
                for (int j = 0; j < 4; ++j) acc[r][j] += ar[r] * wr[j];
        }
        __syncthreads();
    }
    float4 bv = *(const float4*)(bias + n0 + cg * 4);
    float bvr[4] = {bv.x, bv.y, bv.z, bv.w};
#pragma unroll
    for (int r = 0; r < 4; ++r) {
        float o[4];
#pragma unroll
        for (int j = 0; j < 4; ++j) {
            float v = acc[r][j] + bvr[j];
            if (ACT == 1) v = 0.5f * v * (1.0f + erff(v * 0.70710678118654752440f));
            o[j] = v;
        }
        *(float4*)(out + (size_t)(m0 + rg * 4 + r) * N + n0 + cg * 4) = *(float4*)&o[0];
    }
}

// ---------------------------------------------------------------------------
// K4: attention + expert softmax + spectral (L @ clusters). Block = 1 batch.
// ---------------------------------------------------------------------------
__global__ __launch_bounds__(256) void attn_spectral_kernel(
        const float* __restrict__ Qg, const float* __restrict__ Kg,
        const float* __restrict__ Vg, const float* __restrict__ ew,
        const float* __restrict__ eb, float* __restrict__ c2) {
    __shared__ float Qs[KCL * 388];   // Q, later C1
    __shared__ float Ks[KCL * 388];   // K, later V
    __shared__ float ewt[NEXP * 388]; // ew transposed [e][d]
    __shared__ float Ss[KCL * 17];
    __shared__ float hws[KCL * 9];
    __shared__ float rds[NEXP];
    __shared__ float Ls[NEXP * NEXP];
    const int b = blockIdx.x, tid = threadIdx.x;
    for (int idx = tid; idx < KCL * DM; idx += 256) {
        int i = idx / DM, d = idx - i * DM;
        size_t g = (size_t)b * KCL * DM + idx;
        Qs[i * 388 + d] = Qg[g];
        Ks[i * 388 + d] = Kg[g];
    }
    for (int idx = tid; idx < DM * NEXP; idx += 256) {
        int d = idx >> 3, e = idx & 7;
        ewt[e * 388 + d] = ew[idx];
    }
    __syncthreads();
    {   // S = Q K^T / sqrt(D), softmax rows
        int i = tid >> 4, j = tid & 15;
        float acc = 0.f;
        for (int d = 0; d < DM; d += 4) {
            float4 q = *(const float4*)&Qs[i * 388 + d];
            float4 k = *(const float4*)&Ks[j * 388 + d];
            acc += q.x * k.x + q.y * k.y + q.z * k.z + q.w * k.w;
        }
        float s = acc / sqrtf((float)DM);
        float mx = s;
#pragma unroll
        for (int off = 8; off >= 1; off >>= 1) mx = fmaxf(mx, __shfl_xor(mx, off));
        float p = expf(s - mx);
        float sm = p;
#pragma unroll
        for (int off = 8; off >= 1; off >>= 1) sm += __shfl_xor(sm, off);
        Ss[i * 17 + j] = p / sm;
    }
    __syncthreads();
    for (int idx = tid; idx < KCL * DM; idx += 256) {
        int i = idx / DM, d = idx - i * DM;
        Ks[i * 388 + d] = Vg[(size_t)b * KCL * DM + idx];
    }
    __syncthreads();
    for (int idx = tid; idx < KCL * DM; idx += 256) {
        int i = idx / DM, d = idx - i * DM;
        float acc = 0.f;
#pragma unroll
        for (int j = 0; j < KCL; ++j) acc += Ss[i * 17 + j] * Ks[j * 388 + d];
        Qs[i * 388 + d] = acc;
    }
    __syncthreads();
    if (tid < 128) {
        int e = tid >> 4, i = tid & 15;
        float l = 0.f;
        for (int d4 = 0; d4 < DM / 4; ++d4) {
            float4 q = *(const float4*)&Qs[i * 388 + d4 * 4];
            float4 w = *(const float4*)&ewt[e * 388 + d4 * 4];
            l += q.x * w.x + q.y * w.y + q.z * w.z + q.w * w.w;
        }
        l += eb[e];
        float mx = l;
#pragma unroll
        for (int off = 8; off >= 1; off >>= 1) mx = fmaxf(mx, __shfl_xor(mx, off));
        float p = expf(l - mx);
        float sm = p;
#pragma unroll
        for (int off = 8; off >= 1; off >>= 1) sm += __shfl_xor(sm, off);
        float hh = p / sm;
        hws[i * 9 + e] = hh;
        float sd = hh;
#pragma unroll
        for (int off = 8; off >= 1; off >>= 1) sd += __shfl_xor(sd, off);
        if (i == 0) rds[e] = 1.0f / sqrtf(sd);
    }
    __syncthreads();
    if (tid < 64) {
        int e = tid >> 3, f = tid & 7;
        float gsum = 0.f;
#pragma unroll
        for (int k = 0; k < KCL; ++k) gsum += hws[k * 9 + e] * hws[k * 9 + f];
        Ls[e * 8 + f] = ((e == f) ? 1.0f : 0.0f) - rds[e] * gsum;
    }
    __syncthreads();
    for (int idx = tid; idx < KCL * DM; idx += 256) {
        int i = idx / DM, d = idx - i * DM;
        float acc = 0.f;
        if (i < NEXP) {
#pragma unroll
            for (int j = 0; j < NEXP; ++j) acc += Ls[i * 8 + j] * Qs[j * 388 + d];
        }
        c2[(size_t)b * KCL * DM + idx] = acc;
    }
}

// ---------------------------------------------------------------------------
// K6: normalize rows, sim = nc @ nc^T, OR (sim>0.9) into global mask
// ---------------------------------------------------------------------------
__global__ __launch_bounds__(256) void simmask_kernel(const float* __restrict__ c4,
                                                      int* __restrict__ mask) {
    __shared__ float Cs[KCL * 388];
    __shared__ float rns[KCL];
    const int b = blockIdx.x, tid = threadIdx.x;
    for (int idx = tid; idx < KCL * DM; idx += 256) {
        int i = idx / DM, d = idx - i * DM;
        Cs[i * 388 + d] = c4[(size_t)b * KCL * DM + idx];
    }
    __syncthreads();
    {
        int i = tid >> 4, s = tid & 15;
        float ss = 0.f;
        for (int t = 0; t < 24; ++t) { float v = Cs[i * 388 + s + 16 * t]; ss += v * v; }
#pragma unroll
        for (int off = 8; off >= 1; off >>= 1) ss += __shfl_xor(ss, off);
        if (s == 0) rns[i] = 1.0f / fmaxf(sqrtf(ss), 1e-12f);
    }
    __syncthreads();
    for (int idx = tid; idx < KCL * DM; idx += 256) {
        int i = idx / DM, d = idx - i * DM;
        Cs[i * 388 + d] *= rns[i];
    }
    __syncthreads();
    {
        int i = tid >> 4, j = tid & 15;
        if (j > i) {
            float dp = 0.f;
            for (int d = 0; d < DM; d += 4) {
                float4 a = *(const float4*)&Cs[i * 388 + d];
                float4 c = *(const float4*)&Cs[j * 388 + d];
                dp += a.x * c.x + a.y * c.y + a.z * c.z + a.w * c.w;
            }
            if (dp > 0.9f) atomicOr(&mask[i * KCL + j], 1);
        }
    }
}

// ---------------------------------------------------------------------------
// K7: sequential pairwise merge + mean + feedback gate -> c5
// ---------------------------------------------------------------------------
__global__ __launch_bounds__(256) void merge_fb_kernel(
        const float* __restrict__ c4, const int* __restrict__ mask,
        const float* __restrict__ fbw, const float* __restrict__ fbb,
        const float* __restrict__ fgw, const float* __restrict__ fgb,
        float* __restrict__ c5) {
    __shared__ int   mk[256];
    __shared__ float gs[DM];
    __shared__ float wred[3];
    __shared__ float gatev;
    const int b = blockIdx.x, tid = threadIdx.x;
    mk[tid] = mask[tid];
    const bool act = tid < 192;
    const int t = tid;
    float2 v[KCL];
    if (act) {
#pragma unroll
        for (int i = 0; i < KCL; ++i)
            v[i] = *(const float2*)(c4 + (size_t)b * KCL * DM + i * DM + 2 * t);
    }
    __syncthreads();
    if (act) {
#pragma unroll
        for (int i = 0; i < KCL; ++i)
#pragma unroll
            for (int j = i + 1; j < KCL; ++j)
                if (mk[i * KCL + j]) {
                    float mx = 0.5f * (v[i].x + v[j].x);
                    float my = 0.5f * (v[i].y + v[j].y);
                    v[i].x = mx; v[i].y = my; v[j].x = mx; v[j].y = my;
                }
    }
    float2 gv = {0.f, 0.f};
    if (act) {
#pragma unroll
        for (int i = 0; i < KCL; ++i) { gv.x += v[i].x; gv.y += v[i].y; }
        gv.x *= 0.0625f; gv.y *= 0.0625f;
        gs[2 * t] = gv.x; gs[2 * t + 1] = gv.y;
    }
    float pg = act ? (gv.x * fgw[2 * t] + gv.y * fgw[2 * t + 1]) : 0.f;
#pragma unroll
    for (int off = 32; off >= 1; off >>= 1) pg += __shfl_xor(pg, off);
    if (act && (tid & 63) == 0) wred[tid >> 6] = pg;
    __syncthreads();
    if (tid == 0) {
        float d = wred[0] + wred[1] + wred[2] + fgb[0];
        gatev = 1.0f / (1.0f + expf(-d));
    }
    __syncthreads();
    if (act) {
        float fx = fbb[2 * t], fy = fbb[2 * t + 1];
        for (int j = 0; j < DM; ++j) {
            float gj = gs[j];
            const float2 w = *(const float2*)(fbw + (size_t)j * DM + 2 * t);
            fx += gj * w.x; fy += gj * w.y;
        }
        float gt = gatev;
#pragma unroll
        for (int i = 0; i < KCL; ++i) {
            float2 o = {v[i].x + fx * gt, v[i].y + fy * gt};
            *(float2*)(c5 + (size_t)b * KCL * DM + i * DM + 2 * t) = o;
        }
    }
}

// ---------------------------------------------------------------------------
// K8: classifier, split-K with fp32 atomics. out pre-initialized with cb.
// ---------------------------------------------------------------------------
__global__ __launch_bounds__(256) void cls_kernel(const float* __restrict__ A,
                                                  const float* __restrict__ Wt,
                                                  float* __restrict__ out) {
    __shared__ float As[32 * 32];
    __shared__ float Ws[32 * 128];
    const int n0 = blockIdx.x * 128;
    const int m0 = blockIdx.y * 32;
    const int k0 = blockIdx.z * 768;
    const int tid = threadIdx.x;
    const int rg = tid >> 5, cg = tid & 31;
    const int arow = tid >> 3, akg = tid & 7;
    float acc[4][4];
#pragma unroll
    for (int r = 0; r < 4; ++r)
#pragma unroll
        for (int j = 0; j < 4; ++j) acc[r][j] = 0.f;

    for (int kc = k0; kc < k0 + 768; kc += 32) {
        float4 av = *(const float4*)(A + (size_t)(m0 + arow) * (KCL * DM) + kc + akg * 4);
        As[(akg * 4 + 0) * 32 + arow] = av.x;
        As[(akg * 4 + 1) * 32 + arow] = av.y;
        As[(akg * 4 + 2) * 32 + arow] = av.z;
        As[(akg * 4 + 3) * 32 + arow] = av.w;
#pragma unroll
        for (int ti = 0; ti < 4; ++ti) {
            int s = tid + ti * 256;
            int kk = s >> 5, c4i = s & 31;
            int col = n0 + c4i * 4;
            float4 wv = make_float4(0.f, 0.f, 0.f, 0.f);
            if (col < NCLS) wv = *(const float4*)(Wt + (size_t)(kc + kk) * NCLS + col);
            *(float4*)&Ws[kk * 128 + c4i * 4] = wv;
        }
        __syncthreads();
#pragma unroll 16
        for (int kk = 0; kk < 32; ++kk) {
            float4 a = *(const float4*)&As[kk * 32 + rg * 4];
            float4 w = *(const float4*)&Ws[kk * 128 + cg * 4];
            float ar[4] = {a.x, a.y, a.z, a.w};
            float wr[4] = {w.x, w.y, w.z, w.w};
#pragma unroll
            for (int r = 0; r < 4; ++r)
#pragma unroll
                for (int j = 0; j < 4; ++j) acc[r][j] += ar[r] * wr[j];
        }
        __syncthreads();
    }
    int col = n0 + cg * 4;
    if (col < NCLS) {
#pragma unroll
        for (int r = 0; r < 4; ++r) {
            int row = m0 + rg * 4 + r;
#pragma unroll
            for (int j = 0; j < 4; ++j)
                atomicAdd(&out[(size_t)row * NCLS + col + j], acc[r][j]);
        }
    }
}

// ---------------------------------------------------------------------------
extern "C" void kernel_launch(void* const* d_in, const int* in_sizes, int n_in,
                              void* d_out, int out_size, void* d_ws, size_t ws_size,
                              hipStream_t stream) {
    const float* x   = (const float*)d_in[0];
    const float* pw  = (const float*)d_in[1];
    const float* pb  = (const float*)d_in[2];
    const float* lng = (const float*)d_in[3];
    const float* lnb = (const float*)d_in[4];
    const float* pos = (const float*)d_in[5];
    const float* qw  = (const float*)d_in[6];
    const float* qb  = (const float*)d_in[7];
    const float* kw  = (const float*)d_in[8];
    const float* kb  = (const float*)d_in[9];
    const float* vw  = (const float*)d_in[10];
    const float* vb  = (const float*)d_in[11];
    const float* ew  = (const float*)d_in[12];
    const float* eb  = (const float*)d_in[13];
    const float* nw  = (const float*)d_in[14];
    const float* nb  = (const float*)d_in[15];
    const float* m1w = (const float*)d_in[16];
    const float* m1b = (const float*)d_in[17];
    const float* m2w = (const float*)d_in[18];
    const float* m2b = (const float*)d_in[19];
    const float* fbw = (const float*)d_in[20];
    const float* fbb = (const float*)d_in[21];
    const float* fgw = (const float*)d_in[22];
    const float* fgb = (const float*)d_in[23];
    const float* cw  = (const float*)d_in[24];
    const float* cb  = (const float*)d_in[25];
    float* out = (float*)d_out;
    float* ws  = (float*)d_ws;

    // workspace layout (floats)
    float* pn_   = ws;                    // 128*196*384 = 9,633,792
    float* pnsq_ = ws + 9633792;          // 25,088
    float* c0_   = ws + 9658880;          // 786,432 (clusters0; later c5)
    float* Q_    = ws + 10445312;         // 786,432 (later c3)
    float* K_    = ws + 11231744;         // 786,432 (later h)
    float* V_    = ws + 12018176;         // 786,432 (later c4)
    float* c2_   = ws + 12804608;         // 786,432
    int*   mask_ = (int*)(ws + 13591040); // 256 ints
    int*   gcnt_ = (int*)(ws + 13595392); // 4096 ints
    float* gsums_= Q_;                    // 128*2*16*384 = 1,572,864 floats
                                          //  spans Q_+K_ (dead during kmeans)
    float* c3_ = Q_;
    float* h_  = K_;
    float* c4_ = V_;
    float* c5_ = c0_;

    init_kernel<<<501, 256, 0, stream>>>(cb, out, mask_);
    patch_ln_kernel<<<392, 256, 0, stream>>>(x, pw, pb, lng, lnb, pn_, pnsq_);

    {   // cooperative k-means: 256 blocks = 1/CU, all co-resident
        void* args[] = {(void*)&pn_, (void*)&pnsq_, (void*)&pos,
                        (void*)&gsums_, (void*)&gcnt_, (void*)&c0_};
        hipLaunchCooperativeKernel((void*)kmeans_coop_kernel, dim3(2, NBATCH),
                                   dim3(256), args, 0, stream);
    }

    gemm_qkv_kernel<<<dim3(3, 64), 256, 0, stream>>>(c0_, qw, kw, vw, qb, kb, vb,
                                                     Q_, K_, V_);
    attn_spectral_kernel<<<NBATCH, 256, 0, stream>>>(Q_, K_, V_, ew, eb, c2_);
    gemm_kernel<0><<<dim3(3, 64), 256, 0, stream>>>(c2_, nw, nb, c3_, 2048, DM, DM);
    gemm_kernel<1><<<dim3(3, 64), 256, 0, stream>>>(c3_, m1w, m1b, h_, 2048, DM, DM);
    gemm_kernel<0><<<dim3(3, 64), 256, 0, stream>>>(h_, m2w, m2b, c4_, 2048, DM, DM);
    simmask_kernel<<<NBATCH, 256, 0, stream>>>(c4_, mask_);
    merge_fb_kernel<<<NBATCH, 256, 0, stream>>>(c4_, mask_, fbw, fbb, fgw, fgb, c5_);
    cls_kernel<<<dim3(8, 4, 8), 256, 0, stream>>>(c5_, cw, out);
}

// Round 7
// 1457.681 us; speedup vs baseline: 1.3285x; 1.3285x over previous
//
#include <hip/hip_runtime.h>
#include <math.h>

// Shapes (fixed by the problem)
#define NBATCH 128
#define NPTS   196     // 14*14 patches
#define DIN    768     // 3*16*16
#define DM     384
#define KCL    16
#define NEXP   8
#define NITER  10
#define NCLS   1000

// ---------------------------------------------------------------------------
// K0: init out = cb (classifier bias), zero the merge mask
// ---------------------------------------------------------------------------
__global__ __launch_bounds__(256) void init_kernel(const float* __restrict__ cb,
                                                   float* __restrict__ out,
                                                   int* __restrict__ mask) {
    int idx = blockIdx.x * 256 + threadIdx.x;
    if (idx < NBATCH * NCLS) {
        out[idx] = cb[idx % NCLS];
    } else if (idx < NBATCH * NCLS + 256) {
        mask[idx - NBATCH * NCLS] = 0;
    }
}

// ---------------------------------------------------------------------------
// K1: patch extraction + GEMM (25088x768 @ 768x384) + bias + LayerNorm + pnsq
// Round-4 measured-best: 256 threads, BM=64, BK=16, micro 8x12, 251 us.
// ---------------------------------------------------------------------------
#define BKP 16
__global__ __launch_bounds__(256) void patch_ln_kernel(
        const float* __restrict__ x, const float* __restrict__ pw,
        const float* __restrict__ pb, const float* __restrict__ lng,
        const float* __restrict__ lnb, float* __restrict__ pn,
        float* __restrict__ pnsq) {
    __shared__ float As[BKP * 68];   // [kk][row], 64 rows + 4 pad
    __shared__ float Ws[BKP * DM];   // [kk][col]
    const int tid = threadIdx.x;
    const int m0  = blockIdx.x * 64;
    const int rg  = tid >> 5, cg = tid & 31;   // 8 row-groups x 32 col-groups
    const int lr = tid >> 2, kq = tid & 3;     // 64 loader rows x 4 k-quads
    const int m  = m0 + lr;
    const int bi = m / NPTS, n = m - bi * NPTS;
    const int nh = n / 14, nwp = n - nh * 14;
    const float* xb = x + (size_t)bi * 150528 + (size_t)(nh * 16) * 224 + nwp * 16;

    float acc[8][12];
#pragma unroll
    for (int r = 0; r < 8; ++r)
#pragma unroll
        for (int j = 0; j < 12; ++j) acc[r][j] = 0.f;

    const float4* pw4 = (const float4*)pw;
    for (int kc = 0; kc < DIN; kc += BKP) {
        {   // stage A: each thread one float4 (4 consecutive k, same row)
            int k = kc + kq * 4;
            int c = k >> 8, py = (k >> 4) & 15, px = k & 15;
            float4 xv = *(const float4*)(xb + c * 50176 + py * 224 + px);
            As[(kq * 4 + 0) * 68 + lr] = xv.x;
            As[(kq * 4 + 1) * 68 + lr] = xv.y;
            As[(kq * 4 + 2) * 68 + lr] = xv.z;
            As[(kq * 4 + 3) * 68 + lr] = xv.w;
        }
#pragma unroll
        for (int t = 0; t < 6; ++t) {
            int s = tid + t * 256;
            ((float4*)Ws)[s] = pw4[kc * 96 + s];
        }
        __syncthreads();
#pragma unroll 2
        for (int kk = 0; kk < BKP; ++kk) {
            float a[8];
            *(float4*)&a[0] = *(const float4*)&As[kk * 68 + rg * 8];
            *(float4*)&a[4] = *(const float4*)&As[kk * 68 + rg * 8 + 4];
            float w[12];
            *(float4*)&w[0] = *(const float4*)&Ws[kk * DM + cg * 12];
            *(float4*)&w[4] = *(const float4*)&Ws[kk * DM + cg * 12 + 4];
            *(float4*)&w[8] = *(const float4*)&Ws[kk * DM + cg * 12 + 8];
#pragma unroll
            for (int r = 0; r < 8; ++r)
#pragma unroll
                for (int j = 0; j < 12; ++j) acc[r][j] += a[r] * w[j];
        }
        __syncthreads();
    }

    float gvv[12], bvv[12], pbv[12];
#pragma unroll
    for (int j4 = 0; j4 < 3; ++j4) {
        *(float4*)&pbv[j4 * 4] = *(const float4*)(pb + cg * 12 + j4 * 4);
        *(float4*)&gvv[j4 * 4] = *(const float4*)(lng + cg * 12 + j4 * 4);
        *(float4*)&bvv[j4 * 4] = *(const float4*)(lnb + cg * 12 + j4 * 4);
    }
#pragma unroll
    for (int r = 0; r < 8; ++r) {
        float vloc[12];
        float s = 0.f;
#pragma unroll
        for (int j = 0; j < 12; ++j) { vloc[j] = acc[r][j] + pbv[j]; s += vloc[j]; }
#pragma unroll
        for (int off = 16; off >= 1; off >>= 1) s += __shfl_xor(s, off);
        float mu = s * (1.0f / DM);
        float q = 0.f;
#pragma unroll
        for (int j = 0; j < 12; ++j) { float dd = vloc[j] - mu; q += dd * dd; }
#pragma unroll
        for (int off = 16; off >= 1; off >>= 1) q += __shfl_xor(q, off);
        float rstd = rsqrtf(q * (1.0f / DM) + 1e-5f);
        float ov[12];
        float ssq = 0.f;
#pragma unroll
        for (int j = 0; j < 12; ++j) {
            float p = (vloc[j] - mu) * rstd * gvv[j] + bvv[j];
            ov[j] = p; ssq += p * p;
        }
#pragma unroll
        for (int off = 16; off >= 1; off >>= 1) ssq += __shfl_xor(ssq, off);
        int mr = m0 + rg * 8 + r;
        float* dst = pn + (size_t)mr * DM + cg * 12;
        *(float4*)(dst)     = *(float4*)&ov[0];
        *(float4*)(dst + 4) = *(float4*)&ov[4];
        *(float4*)(dst + 8) = *(float4*)&ov[8];
        if (cg == 0) pnsq[mr] = ssq;
    }
}

// ---------------------------------------------------------------------------
// K2: ENTIRE k-means in one persistent per-batch kernel. 128 blocks x 512 thr.
// Centers live in LDS for all 10 iterations; ONLY block-local syncs (no
// grid.sync — measured ~55us each on this chip, round 6).
// Per iter: phase1 assignment (4 pts/lane, 8 sub-lanes, proven association:
// d4=sub+8i ascending, shfl-xor 1,2,4, strict-< first-min argmin);
// ballot masks; phase2 per-column sums ascending over n (same association as
// round-5 update), counts via popcount (deterministic); in-place center
// update with empty-cluster fallback (old value stays); csq 16-su pattern.
// Finally c0 = centers + pos.
// ---------------------------------------------------------------------------
__global__ __launch_bounds__(512) void kmeans_kernel(
        const float* __restrict__ pn, const float* __restrict__ pnsq,
        const float* __restrict__ pos, float* __restrict__ c0) {
    __shared__ float cs[KCL * DM];      // 24 KB centers
    __shared__ float cq[KCL];
    __shared__ int   asn_s[NPTS];
    __shared__ unsigned long long mskS[KCL * 4];
    const int b = blockIdx.x, tid = threadIdx.x;
    const float4* pn4 = (const float4*)(pn + (size_t)b * NPTS * DM);
    float4* cs4 = (float4*)cs;

    // init centers = pn[13k]
    for (int i = tid; i < KCL * 96; i += 512) {
        int k = i / 96, d4 = i - k * 96;
        cs4[i] = pn4[(size_t)(13 * k) * 96 + d4];
    }
    __syncthreads();
    if (tid < 256) {   // initial csq
        int k = tid >> 4, su = tid & 15;
        float ss = 0.f;
        for (int t = 0; t < 24; ++t) { float v = cs[k * DM + su + 16 * t]; ss += v * v; }
#pragma unroll
        for (int off = 8; off >= 1; off >>= 1) ss += __shfl_xor(ss, off);
        if (su == 0) cq[k] = ss;
    }
    __syncthreads();

    const int sub = tid & 7, pg = tid >> 3;    // 64 pgs; 49 active (49*4=196)
    const int n0 = pg * 4;
    const bool act1 = (n0 < NPTS);
    const float* prow[4];
    float mp[4];
#pragma unroll
    for (int pp = 0; pp < 4; ++pp) {
        int np = n0 + pp; if (np > NPTS - 1) np = NPTS - 1;
        prow[pp] = pn + ((size_t)b * NPTS + np) * DM;
        mp[pp] = pnsq[b * NPTS + np];
    }

    for (int it = 0; it < NITER; ++it) {
        // ---- phase 1: assignment ----
        if (act1) {
            float acc[KCL][4];
#pragma unroll
            for (int k = 0; k < KCL; ++k)
#pragma unroll
                for (int pp = 0; pp < 4; ++pp) acc[k][pp] = 0.f;
            for (int i = 0; i < 12; ++i) {
                const int d4 = sub + 8 * i;
                float4 pv[4];
#pragma unroll
                for (int pp = 0; pp < 4; ++pp) pv[pp] = ((const float4*)prow[pp])[d4];
#pragma unroll
                for (int k = 0; k < KCL; ++k) {
                    const float4 c = *(const float4*)&cs[k * DM + d4 * 4];
#pragma unroll
                    for (int pp = 0; pp < 4; ++pp)
                        acc[k][pp] += pv[pp].x * c.x + pv[pp].y * c.y +
                                      pv[pp].z * c.z + pv[pp].w * c.w;
                }
            }
#pragma unroll
            for (int k = 0; k < KCL; ++k)
#pragma unroll
                for (int pp = 0; pp < 4; ++pp) {
                    float a = acc[k][pp];
                    a += __shfl_xor(a, 1);
                    a += __shfl_xor(a, 2);
                    a += __shfl_xor(a, 4);
                    acc[k][pp] = a;
                }
            if (sub < 4) {
                const int pp = sub, n = n0 + pp;
                float best = (mp[pp] - 2.0f * acc[0][pp]) + cq[0];
                int bk = 0;
#pragma unroll
                for (int k = 1; k < KCL; ++k) {
                    float v = (mp[pp] - 2.0f * acc[k][pp]) + cq[k];
                    if (v < best) { best = v; bk = k; }  // strict <: first min
                }
                asn_s[n] = bk;
            }
        }
        __syncthreads();

        // ---- build ballot masks (waves 0..3 cover points 0..195) ----
        if (tid < 256) {
            int a = (tid < NPTS) ? asn_s[tid] : -1;
            int wv = tid >> 6;
#pragma unroll
            for (int k = 0; k < KCL; ++k) {
                unsigned long long bal = __ballot(a == k);
                if ((tid & 63) == 0) mskS[k * 4 + wv] = bal;
            }
        }
        __syncthreads();

        // ---- phase 2: per-column sums (ascending n), in-place update ----
        if (tid < 192) {
            const int c2i = 2 * tid;
            const float* base = pn + (size_t)b * NPTS * DM + c2i;
#pragma unroll
            for (int k = 0; k < KCL; ++k) {
                unsigned long long w0 = mskS[k * 4 + 0], w1 = mskS[k * 4 + 1];
                unsigned long long w2 = mskS[k * 4 + 2], w3 = mskS[k * 4 + 3];
                int c = __popcll(w0) + __popcll(w1) + __popcll(w2) + __popcll(w3);
                float sx = 0.f, sy = 0.f;
                unsigned long long ms[4] = {w0, w1, w2, w3};
#pragma unroll
                for (int w = 0; w < 4; ++w) {
                    unsigned long long m = ms[w];
                    while (m) {
                        int nn = w * 64 + (int)__builtin_ctzll(m);
                        m &= m - 1;
                        float2 v = *(const float2*)(base + (size_t)nn * DM);
                        sx += v.x; sy += v.y;
                    }
                }
                if (c > 0) {
                    float inv = 1.0f / (float)c;
                    cs[k * DM + c2i]     = sx * inv;
                    cs[k * DM + c2i + 1] = sy * inv;
                }   // else: old center stays (fallback)
            }
        }
        __syncthreads();

        // ---- csq of new centers ----
        if (tid < 256) {
            int k = tid >> 4, su = tid & 15;
            float ss = 0.f;
            for (int t = 0; t < 24; ++t) { float v = cs[k * DM + su + 16 * t]; ss += v * v; }
#pragma unroll
            for (int off = 8; off >= 1; off >>= 1) ss += __shfl_xor(ss, off);
            if (su == 0) cq[k] = ss;
        }
        __syncthreads();
    }

    // finalize: c0 = centers + pos
    const float4* pos4 = (const float4*)pos;
    float4* c04 = (float4*)(c0 + (size_t)b * KCL * DM);
    for (int i = tid; i < KCL * 96; i += 512) {
        float4 cv = cs4[i];
        float4 pv = pos4[i];
        c04[i] = make_float4(cv.x + pv.x, cv.y + pv.y, cv.z + pv.z, cv.w + pv.w);
    }
}

// ---------------------------------------------------------------------------
// K3: fused QKV GEMM: 3 outputs from one A-tile staging. BM=32, BN=128, BK=32.
// ---------------------------------------------------------------------------
__global__ __launch_bounds__(256) void gemm_qkv_kernel(
        const float* __restrict__ A,
        const float* __restrict__ qw, const float* __restrict__ kw,
        const float* __restrict__ vw,
        const float* __restrict__ qb, const float* __restrict__ kb,
        const float* __restrict__ vb,
        float* __restrict__ Q, float* __restrict__ K, float* __restrict__ V) {
    __shared__ float As[32 * 32];
    __shared__ float Ws[3][32 * 128];
    const int n0 = blockIdx.x * 128;
    const int m0 = blockIdx.y * 32;
    const int tid = threadIdx.x;
    const int rg = tid >> 5, cg = tid & 31;
    const int arow = tid >> 3, akg = tid & 7;
    const float* W[3] = {qw, kw, vw};

    float acc[3][4][4];
#pragma unroll
    for (int g = 0; g < 3; ++g)
#pragma unroll
        for (int r = 0; r < 4; ++r)
#pragma unroll
            for (int j = 0; j < 4; ++j) acc[g][r][j] = 0.f;

    for (int kc = 0; kc < DM; kc += 32) {
        float4 av = *(const float4*)(A + (size_t)(m0 + arow) * DM + kc + akg * 4);
        As[(akg * 4 + 0) * 32 + arow] = av.x;
        As[(akg * 4 + 1) * 32 + arow] = av.y;
        As[(akg * 4 + 2) * 32 + arow] = av.z;
        As[(akg * 4 + 3) * 32 + arow] = av.w;
#pragma unroll
        for (int g = 0; g < 3; ++g)
#pragma unroll
            for (int t = 0; t < 4; ++t) {
                int s = tid + t * 256;
                int kk = s >> 5, c4i = s & 31;
                *(float4*)&Ws[g][kk * 128 + c4i * 4] =
                    *(const float4*)(W[g] + (size_t)(kc + kk) * DM + n0 + c4i * 4);
            }
        __syncthreads();
#pragma unroll 8
        for (int kk = 0; kk < 32; ++kk) {
            float4 a = *(const float4*)&As[kk * 32 + rg * 4];
            float ar[4] = {a.x, a.y, a.z, a.w};
#pragma unroll
            for (int g = 0; g < 3; ++g) {
                float4 w = *(const float4*)&Ws[g][kk * 128 + cg * 4];
                float wr[4] = {w.x, w.y, w.z, w.w};
#pragma unroll
                for (int r = 0; r < 4; ++r)
#pragma unroll
                    for (int j = 0; j < 4; ++j) acc[g][r][j] += ar[r] * wr[j];
            }
        }
        __syncthreads();
    }
    const float* B[3] = {qb, kb, vb};
    float* O[3] = {Q, K, V};
#pragma unroll
    for (int g = 0; g < 3; ++g) {
        float4 bv = *(const float4*)(B[g] + n0 + cg * 4);
        float bvr[4] = {bv.x, bv.y, bv.z, bv.w};
#pragma unroll
        for (int r = 0; r < 4; ++r) {
            float o[4];
#pragma unroll
            for (int j = 0; j < 4; ++j) o[j] = acc[g][r][j] + bvr[j];
            *(float4*)(O[g] + (size_t)(m0 + rg * 4 + r) * DM + n0 + cg * 4) =
                *(float4*)&o[0];
        }
    }
}

// ---------------------------------------------------------------------------
// Generic fp32 GEMM: out(MxN) = A(MxK) @ W(KxN) + bias, optional exact GELU.
// ---------------------------------------------------------------------------
template <int ACT>
__global__ __launch_bounds__(256) void gemm_kernel(
        const float* __restrict__ A, const float* __restrict__ W,
        const float* __restrict__ bias, float* __restrict__ out,
        int M, int N, int Kd) {
    __shared__ float As[32 * 32];
    __shared__ float Ws[32 * 128];
    const int n0 = blockIdx.x * 128;
    const int m0 = blockIdx.y * 32;
    const int tid = threadIdx.x;
    const int rg = tid >> 5, cg = tid & 31;
    const int arow = tid >> 3, akg = tid & 7;
    float acc[4][4];
#pragma unroll
    for (int r = 0; r < 4; ++r)
#pragma unroll
        for (int j = 0; j < 4; ++j) acc[r][j] = 0.f;

    for (int kc = 0; kc < Kd; kc += 32) {
        float4 av = *(const float4*)(A + (size_t)(m0 + arow) * Kd + kc + akg * 4);
        As[(akg * 4 + 0) * 32 + arow] = av.x;
        As[(akg * 4 + 1) * 32 + arow] = av.y;
        As[(akg * 4 + 2) * 32 + arow] = av.z;
        As[(akg * 4 + 3) * 32 + arow] = av.w;
#pragma unroll
        for (int t = 0; t < 4; ++t) {
            int s = tid + t * 256;
            int kk = s >> 5, c4i = s & 31;
            *(float4*)&Ws[kk * 128 + c4i * 4] =
                *(const float4*)(W + (size_t)(kc + kk) * N + n0 + c4i * 4);
        }
        __syncthreads();
#pragma unroll 16
        for (int kk = 0; kk < 32; ++kk) {
            float4 a = *(const float4*)&As[kk * 32 + rg * 4];
            float4 w = *(const float4*)&Ws[kk * 128 + cg * 4];
            float ar[4] = {a.x, a.y, a.z, a.w};
            float wr[4] = {w.x, w.y, w.z, w.w};
#pragma unroll
            for (int r = 0; r < 4; ++r)
#pragma unroll
                for (int j = 0; j < 4; ++j) acc[r][j] += ar[r] * wr[j];
        }
        __syncthreads();
    }
    float4 bv = *(const float4*)(bias + n0 + cg * 4);
    float bvr[4] = {bv.x, bv.y, bv.z, bv.w};
#pragma unroll
    for (int r = 0; r < 4; ++r) {
        float o[4];
#pragma unroll
        for (int j = 0; j < 4; ++j) {
            float v = acc[r][j] + bvr[j];
            if (ACT == 1) v = 0.5f * v * (1.0f + erff(v * 0.70710678118654752440f));
            o[j] = v;
        }
        *(float4*)(out + (size_t)(m0 + rg * 4 + r) * N + n0 + cg * 4) = *(float4*)&o[0];
    }
}

// ---------------------------------------------------------------------------
// K4: attention + expert softmax + spectral (L @ clusters). Block = 1 batch.
// ---------------------------------------------------------------------------
__global__ __launch_bounds__(256) void attn_spectral_kernel(
        const float* __restrict__ Qg, const float* __restrict__ Kg,
        const float* __restrict__ Vg, const float* __restrict__ ew,
        const float* __restrict__ eb, float* __restrict__ c2) {
    __shared__ float Qs[KCL * 388];   // Q, later C1
    __shared__ float Ks[KCL * 388];   // K, later V
    __shared__ float ewt[NEXP * 388]; // ew transposed [e][d]
    __shared__ float Ss[KCL * 17];
    __shared__ float hws[KCL * 9];
    __shared__ float rds[NEXP];
    __shared__ float Ls[NEXP * NEXP];
    const int b = blockIdx.x, tid = threadIdx.x;
    for (int idx = tid; idx < KCL * DM; idx += 256) {
        int i = idx / DM, d = idx - i * DM;
        size_t g = (size_t)b * KCL * DM + idx;
        Qs[i * 388 + d] = Qg[g];
        Ks[i * 388 + d] = Kg[g];
    }
    for (int idx = tid; idx < DM * NEXP; idx += 256) {
        int d = idx >> 3, e = idx & 7;
        ewt[e * 388 + d] = ew[idx];
    }
    __syncthreads();
    {   // S = Q K^T / sqrt(D), softmax rows
        int i = tid >> 4, j = tid & 15;
        float acc = 0.f;
        for (int d = 0; d < DM; d += 4) {
            float4 q = *(const float4*)&Qs[i * 388 + d];
            float4 k = *(const float4*)&Ks[j * 388 + d];
            acc += q.x * k.x + q.y * k.y + q.z * k.z + q.w * k.w;
        }
        float s = acc / sqrtf((float)DM);
        float mx = s;
#pragma unroll
        for (int off = 8; off >= 1; off >>= 1) mx = fmaxf(mx, __shfl_xor(mx, off));
        float p = expf(s - mx);
        float sm = p;
#pragma unroll
        for (int off = 8; off >= 1; off >>= 1) sm += __shfl_xor(sm, off);
        Ss[i * 17 + j] = p / sm;
    }
    __syncthreads();
    for (int idx = tid; idx < KCL * DM; idx += 256) {
        int i = idx / DM, d = idx - i * DM;
        Ks[i * 388 + d] = Vg[(size_t)b * KCL * DM + idx];
    }
    __syncthreads();
    for (int idx = tid; idx < KCL * DM; idx += 256) {
        int i = idx / DM, d = idx - i * DM;
        float acc = 0.f;
#pragma unroll
        for (int j = 0; j < KCL; ++j) acc += Ss[i * 17 + j] * Ks[j * 388 + d];
        Qs[i * 388 + d] = acc;
    }
    __syncthreads();
    if (tid < 128) {
        int e = tid >> 4, i = tid & 15;
        float l = 0.f;
        for (int d4 = 0; d4 < DM / 4; ++d4) {
            float4 q = *(const float4*)&Qs[i * 388 + d4 * 4];
            float4 w = *(const float4*)&ewt[e * 388 + d4 * 4];
            l += q.x * w.x + q.y * w.y + q.z * w.z + q.w * w.w;
        }
        l += eb[e];
        float mx = l;
#pragma unroll
        for (int off = 8; off >= 1; off >>= 1) mx = fmaxf(mx, __shfl_xor(mx, off));
        float p = expf(l - mx);
        float sm = p;
#pragma unroll
        for (int off = 8; off >= 1; off >>= 1) sm += __shfl_xor(sm, off);
        float hh = p / sm;
        hws[i * 9 + e] = hh;
        float sd = hh;
#pragma unroll
        for (int off = 8; off >= 1; off >>= 1) sd += __shfl_xor(sd, off);
        if (i == 0) rds[e] = 1.0f / sqrtf(sd);
    }
    __syncthreads();
    if (tid < 64) {
        int e = tid >> 3, f = tid & 7;
        float gsum = 0.f;
#pragma unroll
        for (int k = 0; k < KCL; ++k) gsum += hws[k * 9 + e] * hws[k * 9 + f];
        Ls[e * 8 + f] = ((e == f) ? 1.0f : 0.0f) - rds[e] * gsum;
    }
    __syncthreads();
    for (int idx = tid; idx < KCL * DM; idx += 256) {
        int i = idx / DM, d = idx - i * DM;
        float acc = 0.f;
        if (i < NEXP) {
#pragma unroll
            for (int j = 0; j < NEXP; ++j) acc += Ls[i * 8 + j] * Qs[j * 388 + d];
        }
        c2[(size_t)b * KCL * DM + idx] = acc;
    }
}

// ---------------------------------------------------------------------------
// K6: normalize rows, sim = nc @ nc^T, OR (sim>0.9) into global mask
// ---------------------------------------------------------------------------
__global__ __launch_bounds__(256) void simmask_kernel(const float* __restrict__ c4,
                                                      int* __restrict__ mask) {
    __shared__ float Cs[KCL * 388];
    __shared__ float rns[KCL];
    const int b = blockIdx.x, tid = threadIdx.x;
    for (int idx = tid; idx < KCL * DM; idx += 256) {
        int i = idx / DM, d = idx - i * DM;
        Cs[i * 388 + d] = c4[(size_t)b * KCL * DM + idx];
    }
    __syncthreads();
    {
        int i = tid >> 4, s = tid & 15;
        float ss = 0.f;
        for (int t = 0; t < 24; ++t) { float v = Cs[i * 388 + s + 16 * t]; ss += v * v; }
#pragma unroll
        for (int off = 8; off >= 1; off >>= 1) ss += __shfl_xor(ss, off);
        if (s == 0) rns[i] = 1.0f / fmaxf(sqrtf(ss), 1e-12f);
    }
    __syncthreads();
    for (int idx = tid; idx < KCL * DM; idx += 256) {
        int i = idx / DM, d = idx - i * DM;
        Cs[i * 388 + d] *= rns[i];
    }
    __syncthreads();
    {
        int i = tid >> 4, j = tid & 15;
        if (j > i) {
            float dp = 0.f;
            for (int d = 0; d < DM; d += 4) {
                float4 a = *(const float4*)&Cs[i * 388 + d];
                float4 c = *(const float4*)&Cs[j * 388 + d];
                dp += a.x * c.x + a.y * c.y + a.z * c.z + a.w * c.w;
            }
            if (dp > 0.9f) atomicOr(&mask[i * KCL + j], 1);
        }
    }
}

// ---------------------------------------------------------------------------
// K7: sequential pairwise merge + mean + feedback gate -> c5
// ---------------------------------------------------------------------------
__global__ __launch_bounds__(256) void merge_fb_kernel(
        const float* __restrict__ c4, const int* __restrict__ mask,
        const float* __restrict__ fbw, const float* __restrict__ fbb,
        const float* __restrict__ fgw, const float* __restrict__ fgb,
        float* __restrict__ c5) {
    __shared__ int   mk[256];
    __shared__ float gs[DM];
    __shared__ float wred[3];
    __shared__ float gatev;
    const int b = blockIdx.x, tid = threadIdx.x;
    mk[tid] = mask[tid];
    const bool act = tid < 192;
    const int t = tid;
    float2 v[KCL];
    if (act) {
#pragma unroll
        for (int i = 0; i < KCL; ++i)
            v[i] = *(const float2*)(c4 + (size_t)b * KCL * DM + i * DM + 2 * t);
    }
    __syncthreads();
    if (act) {
#pragma unroll
        for (int i = 0; i < KCL; ++i)
#pragma unroll
            for (int j = i + 1; j < KCL; ++j)
                if (mk[i * KCL + j]) {
                    float mx = 0.5f * (v[i].x + v[j].x);
                    float my = 0.5f * (v[i].y + v[j].y);
                    v[i].x = mx; v[i].y = my; v[j].x = mx; v[j].y = my;
                }
    }
    float2 gv = {0.f, 0.f};
    if (act) {
#pragma unroll
        for (int i = 0; i < KCL; ++i) { gv.x += v[i].x; gv.y += v[i].y; }
        gv.x *= 0.0625f; gv.y *= 0.0625f;
        gs[2 * t] = gv.x; gs[2 * t + 1] = gv.y;
    }
    float pg = act ? (gv.x * fgw[2 * t] + gv.y * fgw[2 * t + 1]) : 0.f;
#pragma unroll
    for (int off = 32; off >= 1; off >>= 1) pg += __shfl_xor(pg, off);
    if (act && (tid & 63) == 0) wred[tid >> 6] = pg;
    __syncthreads();
    if (tid == 0) {
        float d = wred[0] + wred[1] + wred[2] + fgb[0];
        gatev = 1.0f / (1.0f + expf(-d));
    }
    __syncthreads();
    if (act) {
        float fx = fbb[2 * t], fy = fbb[2 * t + 1];
        for (int j = 0; j < DM; ++j) {
            float gj = gs[j];
            const float2 w = *(const float2*)(fbw + (size_t)j * DM + 2 * t);
            fx += gj * w.x; fy += gj * w.y;
        }
        float gt = gatev;
#pragma unroll
        for (int i = 0; i < KCL; ++i) {
            float2 o = {v[i].x + fx * gt, v[i].y + fy * gt};
            *(float2*)(c5 + (size_t)b * KCL * DM + i * DM + 2 * t) = o;
        }
    }
}

// ---------------------------------------------------------------------------
// K8: classifier, split-K with fp32 atomics. out pre-initialized with cb.
// ---------------------------------------------------------------------------
__global__ __launch_bounds__(256) void cls_kernel(const float* __restrict__ A,
                                                  const float* __restrict__ Wt,
                                                  float* __restrict__ out) {
    __shared__ float As[32 * 32];
    __shared__ float Ws[32 * 128];
    const int n0 = blockIdx.x * 128;
    const int m0 = blockIdx.y * 32;
    const int k0 = blockIdx.z * 768;
    const int tid = threadIdx.x;
    const int rg = tid >> 5, cg = tid & 31;
    const int arow = tid >> 3, akg = tid & 7;
    float acc[4][4];
#pragma unroll
    for (int r = 0; r < 4; ++r)
#pragma unroll
        for (int j = 0; j < 4; ++j) acc[r][j] = 0.f;

    for (int kc = k0; kc < k0 + 768; kc += 32) {
        float4 av = *(const float4*)(A + (size_t)(m0 + arow) * (KCL * DM) + kc + akg * 4);
        As[(akg * 4 + 0) * 32 + arow] = av.x;
        As[(akg * 4 + 1) * 32 + arow] = av.y;
        As[(akg * 4 + 2) * 32 + arow] = av.z;
        As[(akg * 4 + 3) * 32 + arow] = av.w;
#pragma unroll
        for (int ti = 0; ti < 4; ++ti) {
            int s = tid + ti * 256;
            int kk = s >> 5, c4i = s & 31;
            int col = n0 + c4i * 4;
            float4 wv = make_float4(0.f, 0.f, 0.f, 0.f);
            if (col < NCLS) wv = *(const float4*)(Wt + (size_t)(kc + kk) * NCLS + col);
            *(float4*)&Ws[kk * 128 + c4i * 4] = wv;
        }
        __syncthreads();
#pragma unroll 16
        for (int kk = 0; kk < 32; ++kk) {
            float4 a = *(const float4*)&As[kk * 32 + rg * 4];
            float4 w = *(const float4*)&Ws[kk * 128 + cg * 4];
            float ar[4] = {a.x, a.y, a.z, a.w};
            float wr[4] = {w.x, w.y, w.z, w.w};
#pragma unroll
            for (int r = 0; r < 4; ++r)
#pragma unroll
                for (int j = 0; j < 4; ++j) acc[r][j] += ar[r] * wr[j];
        }
        __syncthreads();
    }
    int col = n0 + cg * 4;
    if (col < NCLS) {
#pragma unroll
        for (int r = 0; r < 4; ++r) {
            int row = m0 + rg * 4 + r;
#pragma unroll
            for (int j = 0; j < 4; ++j)
                atomicAdd(&out[(size_t)row * NCLS + col + j], acc[r][j]);
        }
    }
}

// ---------------------------------------------------------------------------
extern "C" void kernel_launch(void* const* d_in, const int* in_sizes, int n_in,
                              void* d_out, int out_size, void* d_ws, size_t ws_size,
                              hipStream_t stream) {
    const float* x   = (const float*)d_in[0];
    const float* pw  = (const float*)d_in[1];
    const float* pb  = (const float*)d_in[2];
    const float* lng = (const float*)d_in[3];
    const float* lnb = (const float*)d_in[4];
    const float* pos = (const float*)d_in[5];
    const float* qw  = (const float*)d_in[6];
    const float* qb  = (const float*)d_in[7];
    const float* kw  = (const float*)d_in[8];
    const float* kb  = (const float*)d_in[9];
    const float* vw  = (const float*)d_in[10];
    const float* vb  = (const float*)d_in[11];
    const float* ew  = (const float*)d_in[12];
    const float* eb  = (const float*)d_in[13];
    const float* nw  = (const float*)d_in[14];
    const float* nb  = (const float*)d_in[15];
    const float* m1w = (const float*)d_in[16];
    const float* m1b = (const float*)d_in[17];
    const float* m2w = (const float*)d_in[18];
    const float* m2b = (const float*)d_in[19];
    const float* fbw = (const float*)d_in[20];
    const float* fbb = (const float*)d_in[21];
    const float* fgw = (const float*)d_in[22];
    const float* fgb = (const float*)d_in[23];
    const float* cw  = (const float*)d_in[24];
    const float* cb  = (const float*)d_in[25];
    float* out = (float*)d_out;
    float* ws  = (float*)d_ws;

    // workspace layout (floats)
    float* pn_   = ws;                    // 128*196*384 = 9,633,792
    float* pnsq_ = ws + 9633792;          // 25,088
    float* c0_   = ws + 9658880;          // 786,432 (clusters0; later c5)
    float* Q_    = ws + 10445312;         // 786,432 (later c3)
    float* K_    = ws + 11231744;         // 786,432 (later h)
    float* V_    = ws + 12018176;         // 786,432 (later c4)
    float* c2_   = ws + 12804608;         // 786,432
    int*   mask_ = (int*)(ws + 13591040); // 256 ints
    float* c3_ = Q_;
    float* h_  = K_;
    float* c4_ = V_;
    float* c5_ = c0_;

    init_kernel<<<501, 256, 0, stream>>>(cb, out, mask_);
    patch_ln_kernel<<<392, 256, 0, stream>>>(x, pw, pb, lng, lnb, pn_, pnsq_);
    kmeans_kernel<<<NBATCH, 512, 0, stream>>>(pn_, pnsq_, pos, c0_);
    gemm_qkv_kernel<<<dim3(3, 64), 256, 0, stream>>>(c0_, qw, kw, vw, qb, kb, vb,
                                                     Q_, K_, V_);
    attn_spectral_kernel<<<NBATCH, 256, 0, stream>>>(Q_, K_, V_, ew, eb, c2_);
    gemm_kernel<0><<<dim3(3, 64), 256, 0, stream>>>(c2_, nw, nb, c3_, 2048, DM, DM);
    gemm_kernel<1><<<dim3(3, 64), 256, 0, stream>>>(c3_, m1w, m1b, h_, 2048, DM, DM);
    gemm_kernel<0><<<dim3(3, 64), 256, 0, stream>>>(h_, m2w, m2b, c4_, 2048, DM, DM);
    simmask_kernel<<<NBATCH, 256, 0, stream>>>(c4_, mask_);
    merge_fb_kernel<<<NBATCH, 256, 0, stream>>>(c4_, mask_, fbw, fbb, fgw, fgb, c5_);
    cls_kernel<<<dim3(8, 4, 8), 256, 0, stream>>>(c5_, cw, out);
}

// Round 8
// 1223.605 us; speedup vs baseline: 1.5827x; 1.1913x over previous
//
#include <hip/hip_runtime.h>
#include <math.h>

// Shapes (fixed by the problem)
#define NBATCH 128
#define NPTS   196     // 14*14 patches
#define DIN    768     // 3*16*16
#define DM     384
#define KCL    16
#define NEXP   8
#define NITER  10
#define NCLS   1000

// ---------------------------------------------------------------------------
// K0: init out = cb (classifier bias), zero the merge mask
// ---------------------------------------------------------------------------
__global__ __launch_bounds__(256) void init_kernel(const float* __restrict__ cb,
                                                   float* __restrict__ out,
                                                   int* __restrict__ mask) {
    int idx = blockIdx.x * 256 + threadIdx.x;
    if (idx < NBATCH * NCLS) {
        out[idx] = cb[idx % NCLS];
    } else if (idx < NBATCH * NCLS + 256) {
        mask[idx - NBATCH * NCLS] = 0;
    }
}

// ---------------------------------------------------------------------------
// K1: patch extraction + GEMM (25088x768 @ 768x384) + bias + LayerNorm + pnsq
// Round-4 measured-best: 256 threads, BM=64, BK=16, micro 8x12, 251 us.
// ---------------------------------------------------------------------------
#define BKP 16
__global__ __launch_bounds__(256) void patch_ln_kernel(
        const float* __restrict__ x, const float* __restrict__ pw,
        const float* __restrict__ pb, const float* __restrict__ lng,
        const float* __restrict__ lnb, float* __restrict__ pn,
        float* __restrict__ pnsq) {
    __shared__ float As[BKP * 68];   // [kk][row], 64 rows + 4 pad
    __shared__ float Ws[BKP * DM];   // [kk][col]
    const int tid = threadIdx.x;
    const int m0  = blockIdx.x * 64;
    const int rg  = tid >> 5, cg = tid & 31;   // 8 row-groups x 32 col-groups
    const int lr = tid >> 2, kq = tid & 3;     // 64 loader rows x 4 k-quads
    const int m  = m0 + lr;
    const int bi = m / NPTS, n = m - bi * NPTS;
    const int nh = n / 14, nwp = n - nh * 14;
    const float* xb = x + (size_t)bi * 150528 + (size_t)(nh * 16) * 224 + nwp * 16;

    float acc[8][12];
#pragma unroll
    for (int r = 0; r < 8; ++r)
#pragma unroll
        for (int j = 0; j < 12; ++j) acc[r][j] = 0.f;

    const float4* pw4 = (const float4*)pw;
    for (int kc = 0; kc < DIN; kc += BKP) {
        {   // stage A: each thread one float4 (4 consecutive k, same row)
            int k = kc + kq * 4;
            int c = k >> 8, py = (k >> 4) & 15, px = k & 15;
            float4 xv = *(const float4*)(xb + c * 50176 + py * 224 + px);
            As[(kq * 4 + 0) * 68 + lr] = xv.x;
            As[(kq * 4 + 1) * 68 + lr] = xv.y;
            As[(kq * 4 + 2) * 68 + lr] = xv.z;
            As[(kq * 4 + 3) * 68 + lr] = xv.w;
        }
#pragma unroll
        for (int t = 0; t < 6; ++t) {
            int s = tid + t * 256;
            ((float4*)Ws)[s] = pw4[kc * 96 + s];
        }
        __syncthreads();
#pragma unroll 2
        for (int kk = 0; kk < BKP; ++kk) {
            float a[8];
            *(float4*)&a[0] = *(const float4*)&As[kk * 68 + rg * 8];
            *(float4*)&a[4] = *(const float4*)&As[kk * 68 + rg * 8 + 4];
            float w[12];
            *(float4*)&w[0] = *(const float4*)&Ws[kk * DM + cg * 12];
            *(float4*)&w[4] = *(const float4*)&Ws[kk * DM + cg * 12 + 4];
            *(float4*)&w[8] = *(const float4*)&Ws[kk * DM + cg * 12 + 8];
#pragma unroll
            for (int r = 0; r < 8; ++r)
#pragma unroll
                for (int j = 0; j < 12; ++j) acc[r][j] += a[r] * w[j];
        }
        __syncthreads();
    }

    float gvv[12], bvv[12], pbv[12];
#pragma unroll
    for (int j4 = 0; j4 < 3; ++j4) {
        *(float4*)&pbv[j4 * 4] = *(const float4*)(pb + cg * 12 + j4 * 4);
        *(float4*)&gvv[j4 * 4] = *(const float4*)(lng + cg * 12 + j4 * 4);
        *(float4*)&bvv[j4 * 4] = *(const float4*)(lnb + cg * 12 + j4 * 4);
    }
#pragma unroll
    for (int r = 0; r < 8; ++r) {
        float vloc[12];
        float s = 0.f;
#pragma unroll
        for (int j = 0; j < 12; ++j) { vloc[j] = acc[r][j] + pbv[j]; s += vloc[j]; }
#pragma unroll
        for (int off = 16; off >= 1; off >>= 1) s += __shfl_xor(s, off);
        float mu = s * (1.0f / DM);
        float q = 0.f;
#pragma unroll
        for (int j = 0; j < 12; ++j) { float dd = vloc[j] - mu; q += dd * dd; }
#pragma unroll
        for (int off = 16; off >= 1; off >>= 1) q += __shfl_xor(q, off);
        float rstd = rsqrtf(q * (1.0f / DM) + 1e-5f);
        float ov[12];
        float ssq = 0.f;
#pragma unroll
        for (int j = 0; j < 12; ++j) {
            float p = (vloc[j] - mu) * rstd * gvv[j] + bvv[j];
            ov[j] = p; ssq += p * p;
        }
#pragma unroll
        for (int off = 16; off >= 1; off >>= 1) ssq += __shfl_xor(ssq, off);
        int mr = m0 + rg * 8 + r;
        float* dst = pn + (size_t)mr * DM + cg * 12;
        *(float4*)(dst)     = *(float4*)&ov[0];
        *(float4*)(dst + 4) = *(float4*)&ov[4];
        *(float4*)(dst + 8) = *(float4*)&ov[8];
        if (cg == 0) pnsq[mr] = ssq;
    }
}

// ---------------------------------------------------------------------------
// K2: ENTIRE k-means in one persistent per-batch kernel. 128 blocks x 512 thr.
// Round-8 phase-2 fix: the round-7 while(mask){ctz;load;add} chain was a
// serial dependent-load loop (196 x ~400cyc = the whole 800us — VALUBusy 5.6%).
// Now: compact ascending per-cluster index lists (deterministic), then a
// counted loop with EXPLICIT 8-deep load batching (8 independent
// global_load_dwordx2 in flight before any accumulate). Accumulation order
// stays strictly ascending per cluster — identical association to round 5.
// ---------------------------------------------------------------------------
__global__ __launch_bounds__(512) void kmeans_kernel(
        const float* __restrict__ pn, const float* __restrict__ pnsq,
        const float* __restrict__ pos, float* __restrict__ c0) {
    __shared__ float cs[KCL * DM];      // 24 KB centers
    __shared__ float cq[KCL];
    __shared__ int   asn_s[NPTS];
    __shared__ short lst[KCL * NPTS];   // per-cluster ascending point lists
    __shared__ int   cnt_s[KCL];
    const int b = blockIdx.x, tid = threadIdx.x;
    const float4* pn4 = (const float4*)(pn + (size_t)b * NPTS * DM);
    float4* cs4 = (float4*)cs;

    // init centers = pn[13k]
    for (int i = tid; i < KCL * 96; i += 512) {
        int k = i / 96, d4 = i - k * 96;
        cs4[i] = pn4[(size_t)(13 * k) * 96 + d4];
    }
    __syncthreads();
    if (tid < 256) {   // initial csq
        int k = tid >> 4, su = tid & 15;
        float ss = 0.f;
        for (int t = 0; t < 24; ++t) { float v = cs[k * DM + su + 16 * t]; ss += v * v; }
#pragma unroll
        for (int off = 8; off >= 1; off >>= 1) ss += __shfl_xor(ss, off);
        if (su == 0) cq[k] = ss;
    }
    __syncthreads();

    const int sub = tid & 7, pg = tid >> 3;    // 64 pgs; 49 active (49*4=196)
    const int n0 = pg * 4;
    const bool act1 = (n0 < NPTS);
    const float* prow[4];
    float mp[4];
#pragma unroll
    for (int pp = 0; pp < 4; ++pp) {
        int np = n0 + pp; if (np > NPTS - 1) np = NPTS - 1;
        prow[pp] = pn + ((size_t)b * NPTS + np) * DM;
        mp[pp] = pnsq[b * NPTS + np];
    }

    for (int it = 0; it < NITER; ++it) {
        // ---- phase 1: assignment (proven round-4/7 pattern) ----
        if (act1) {
            float acc[KCL][4];
#pragma unroll
            for (int k = 0; k < KCL; ++k)
#pragma unroll
                for (int pp = 0; pp < 4; ++pp) acc[k][pp] = 0.f;
            for (int i = 0; i < 12; ++i) {
                const int d4 = sub + 8 * i;
                float4 pv[4];
#pragma unroll
                for (int pp = 0; pp < 4; ++pp) pv[pp] = ((const float4*)prow[pp])[d4];
#pragma unroll
                for (int k = 0; k < KCL; ++k) {
                    const float4 c = *(const float4*)&cs[k * DM + d4 * 4];
#pragma unroll
                    for (int pp = 0; pp < 4; ++pp)
                        acc[k][pp] += pv[pp].x * c.x + pv[pp].y * c.y +
                                      pv[pp].z * c.z + pv[pp].w * c.w;
                }
            }
#pragma unroll
            for (int k = 0; k < KCL; ++k)
#pragma unroll
                for (int pp = 0; pp < 4; ++pp) {
                    float a = acc[k][pp];
                    a += __shfl_xor(a, 1);
                    a += __shfl_xor(a, 2);
                    a += __shfl_xor(a, 4);
                    acc[k][pp] = a;
                }
            if (sub < 4) {
                const int pp = sub, n = n0 + pp;
                float best = (mp[pp] - 2.0f * acc[0][pp]) + cq[0];
                int bk = 0;
#pragma unroll
                for (int k = 1; k < KCL; ++k) {
                    float v = (mp[pp] - 2.0f * acc[k][pp]) + cq[k];
                    if (v < best) { best = v; bk = k; }  // strict <: first min
                }
                asn_s[n] = bk;
            }
        }
        __syncthreads();

        // ---- build compact ascending per-cluster lists (deterministic) ----
        if (tid < KCL) {
            int c = 0;
            short* lk = &lst[tid * NPTS];
            for (int n = 0; n < NPTS; ++n)          // same-address LDS reads:
                if (asn_s[n] == tid) lk[c++] = (short)n;  // wave broadcast
            cnt_s[tid] = c;
        }
        __syncthreads();

        // ---- phase 2: per-column sums, 8-deep batched loads, ascending ----
        if (tid < 192) {
            const int c2i = 2 * tid;
            const float* base = pn + (size_t)b * NPTS * DM + c2i;
#pragma unroll 1
            for (int k = 0; k < KCL; ++k) {
                const int cnt = cnt_s[k];            // wave-uniform
                const short* lk = &lst[k * NPTS];
                float sx = 0.f, sy = 0.f;
                for (int i = 0; i < cnt; i += 8) {
                    float2 v[8];
#pragma unroll
                    for (int j = 0; j < 8; ++j) {
                        int idx = (i + j < cnt) ? (int)lk[i + j]
                                                : (int)lk[cnt - 1];
                        v[j] = *(const float2*)(base + (size_t)idx * DM);
                    }
#pragma unroll
                    for (int j = 0; j < 8; ++j) {
                        if (i + j < cnt) { sx += v[j].x; sy += v[j].y; }
                    }
                }
                if (cnt > 0) {
                    float inv = 1.0f / (float)cnt;
                    cs[k * DM + c2i]     = sx * inv;
                    cs[k * DM + c2i + 1] = sy * inv;
                }   // else: old center stays (fallback)
            }
        }
        __syncthreads();

        // ---- csq of new centers ----
        if (tid < 256) {
            int k = tid >> 4, su = tid & 15;
            float ss = 0.f;
            for (int t = 0; t < 24; ++t) { float v = cs[k * DM + su + 16 * t]; ss += v * v; }
#pragma unroll
            for (int off = 8; off >= 1; off >>= 1) ss += __shfl_xor(ss, off);
            if (su == 0) cq[k] = ss;
        }
        __syncthreads();
    }

    // finalize: c0 = centers + pos
    const float4* pos4 = (const float4*)pos;
    float4* c04 = (float4*)(c0 + (size_t)b * KCL * DM);
    for (int i = tid; i < KCL * 96; i += 512) {
        float4 cv = cs4[i];
        float4 pv = pos4[i];
        c04[i] = make_float4(cv.x + pv.x, cv.y + pv.y, cv.z + pv.z, cv.w + pv.w);
    }
}

// ---------------------------------------------------------------------------
// K3: fused QKV GEMM: 3 outputs from one A-tile staging. BM=32, BN=128, BK=32.
// ---------------------------------------------------------------------------
__global__ __launch_bounds__(256) void gemm_qkv_kernel(
        const float* __restrict__ A,
        const float* __restrict__ qw, const float* __restrict__ kw,
        const float* __restrict__ vw,
        const float* __restrict__ qb, const float* __restrict__ kb,
        const float* __restrict__ vb,
        float* __restrict__ Q, float* __restrict__ K, float* __restrict__ V) {
    __shared__ float As[32 * 32];
    __shared__ float Ws[3][32 * 128];
    const int n0 = blockIdx.x * 128;
    const int m0 = blockIdx.y * 32;
    const int tid = threadIdx.x;
    const int rg = tid >> 5, cg = tid & 31;
    const int arow = tid >> 3, akg = tid & 7;
    const float* W[3] = {qw, kw, vw};

    float acc[3][4][4];
#pragma unroll
    for (int g = 0; g < 3; ++g)
#pragma unroll
        for (int r = 0; r < 4; ++r)
#pragma unroll
            for (int j = 0; j < 4; ++j) acc[g][r][j] = 0.f;

    for (int kc = 0; kc < DM; kc += 32) {
        float4 av = *(const float4*)(A + (size_t)(m0 + arow) * DM + kc + akg * 4);
        As[(akg * 4 + 0) * 32 + arow] = av.x;
        As[(akg * 4 + 1) * 32 + arow] = av.y;
        As[(akg * 4 + 2) * 32 + arow] = av.z;
        As[(akg * 4 + 3) * 32 + arow] = av.w;
#pragma unroll
        for (int g = 0; g < 3; ++g)
#pragma unroll
            for (int t = 0; t < 4; ++t) {
                int s = tid + t * 256;
                int kk = s >> 5, c4i = s & 31;
                *(float4*)&Ws[g][kk * 128 + c4i * 4] =
                    *(const float4*)(W[g] + (size_t)(kc + kk) * DM + n0 + c4i * 4);
            }
        __syncthreads();
#pragma unroll 8
        for (int kk = 0; kk < 32; ++kk) {
            float4 a = *(const float4*)&As[kk * 32 + rg * 4];
            float ar[4] = {a.x, a.y, a.z, a.w};
#pragma unroll
            for (int g = 0; g < 3; ++g) {
                float4 w = *(const float4*)&Ws[g][kk * 128 + cg * 4];
                float wr[4] = {w.x, w.y, w.z, w.w};
#pragma unroll
                for (int r = 0; r < 4; ++r)
#pragma unroll
                    for (int j = 0; j < 4; ++j) acc[g][r][j] += ar[r] * wr[j];
            }
        }
        __syncthreads();
    }
    const float* B[3] = {qb, kb, vb};
    float* O[3] = {Q, K, V};
#pragma unroll
    for (int g = 0; g < 3; ++g) {
        float4 bv = *(const float4*)(B[g] + n0 + cg * 4);
        float bvr[4] = {bv.x, bv.y, bv.z, bv.w};
#pragma unroll
        for (int r = 0; r < 4; ++r) {
            float o[4];
#pragma unroll
            for (int j = 0; j < 4; ++j) o[j] = acc[g][r][j] + bvr[j];
            *(float4*)(O[g] + (size_t)(m0 + rg * 4 + r) * DM + n0 + cg * 4) =
                *(float4*)&o[0];
        }
    }
}

// ---------------------------------------------------------------------------
// Generic fp32 GEMM: out(MxN) = A(MxK) @ W(KxN) + bias, optional exact GELU.
// ---------------------------------------------------------------------------
template <int ACT>
__global__ __launch_bounds__(256) void gemm_kernel(
        const float* __restrict__ A, const float* __restrict__ W,
        const float* __restrict__ bias, float* __restrict__ out,
        int M, int N, int Kd) {
    __shared__ float As[32 * 32];
    __shared__ float Ws[32 * 128];
    const int n0 = blockIdx.x * 128;
    const int m0 = blockIdx.y * 32;
    const int tid = threadIdx.x;
    const int rg = tid >> 5, cg = tid & 31;
    const int arow = tid >> 3, akg = tid & 7;
    float acc[4][4];
#pragma unroll
    for (int r = 0; r < 4; ++r)
#pragma unroll
        for (int j = 0; j < 4; ++j) acc[r][j] = 0.f;

    for (int kc = 0; kc < Kd; kc += 32) {
        float4 av = *(const float4*)(A + (size_t)(m0 + arow) * Kd + kc + akg * 4);
        As[(akg * 4 + 0) * 32 + arow] = av.x;
        As[(akg * 4 + 1) * 32 + arow] = av.y;
        As[(akg * 4 + 2) * 32 + arow] = av.z;
        As[(akg * 4 + 3) * 32 + arow] = av.w;
#pragma unroll
        for (int t = 0; t < 4; ++t) {
            int s = tid + t * 256;
            int kk = s >> 5, c4i = s & 31;
            *(float4*)&Ws[kk * 128 + c4i * 4] =
                *(const float4*)(W + (size_t)(kc + kk) * N + n0 + c4i * 4);
        }
        __syncthreads();
#pragma unroll 16
        for (int kk = 0; kk < 32; ++kk) {
            float4 a = *(const float4*)&As[kk * 32 + rg * 4];
            float4 w = *(const float4*)&Ws[kk * 128 + cg * 4];
            float ar[4] = {a.x, a.y, a.z, a.w};
            float wr[4] = {w.x, w.y, w.z, w.w};
#pragma unroll
            for (int r = 0; r < 4; ++r)
#pragma unroll
                for (int j = 0; j < 4; ++j) acc[r][j] += ar[r] * wr[j];
        }
        __syncthreads();
    }
    float4 bv = *(const float4*)(bias + n0 + cg * 4);
    float bvr[4] = {bv.x, bv.y, bv.z, bv.w};
#pragma unroll
    for (int r = 0; r < 4; ++r) {
        float o[4];
#pragma unroll
        for (int j = 0; j < 4; ++j) {
            float v = acc[r][j] + bvr[j];
            if (ACT == 1) v = 0.5f * v * (1.0f + erff(v * 0.70710678118654752440f));
            o[j] = v;
        }
        *(float4*)(out + (size_t)(m0 + rg * 4 + r) * N + n0 + cg * 4) = *(float4*)&o[0];
    }
}

// ---------------------------------------------------------------------------
// K4: attention + expert softmax + spectral (L @ clusters). Block = 1 batch.
// ---------------------------------------------------------------------------
__global__ __launch_bounds__(256) void attn_spectral_kernel(
        const float* __restrict__ Qg, const float* __restrict__ Kg,
        const float* __restrict__ Vg, const float* __restrict__ ew,
        const float* __restrict__ eb, float* __restrict__ c2) {
    __shared__ float Qs[KCL * 388];   // Q, later C1
    __shared__ float Ks[KCL * 388];   // K, later V
    __shared__ float ewt[NEXP * 388]; // ew transposed [e][d]
    __shared__ float Ss[KCL * 17];
    __shared__ float hws[KCL * 9];
    __shared__ float rds[NEXP];
    __shared__ float Ls[NEXP * NEXP];
    const int b = blockIdx.x, tid = threadIdx.x;
    for (int idx = tid; idx < KCL * DM; idx += 256) {
        int i = idx / DM, d = idx - i * DM;
        size_t g = (size_t)b * KCL * DM + idx;
        Qs[i * 388 + d] = Qg[g];
        Ks[i * 388 + d] = Kg[g];
    }
    for (int idx = tid; idx < DM * NEXP; idx += 256) {
        int d = idx >> 3, e = idx & 7;
        ewt[e * 388 + d] = ew[idx];
    }
    __syncthreads();
    {   // S = Q K^T / sqrt(D), softmax rows
        int i = tid >> 4, j = tid & 15;
        float acc = 0.f;
        for (int d = 0; d < DM; d += 4) {
            float4 q = *(const float4*)&Qs[i * 388 + d];
            float4 k = *(const float4*)&Ks[j * 388 + d];
            acc += q.x * k.x + q.y * k.y + q.z * k.z + q.w * k.w;
        }
        float s = acc / sqrtf((float)DM);
        float mx = s;
#pragma unroll
        for (int off = 8; off >= 1; off >>= 1) mx = fmaxf(mx, __shfl_xor(mx, off));
        float p = expf(s - mx);
        float sm = p;
#pragma unroll
        for (int off = 8; off >= 1; off >>= 1) sm += __shfl_xor(sm, off);
        Ss[i * 17 + j] = p / sm;
    }
    __syncthreads();
    for (int idx = tid; idx < KCL * DM; idx += 256) {
        int i = idx / DM, d = idx - i * DM;
        Ks[i * 388 + d] = Vg[(size_t)b * KCL * DM + idx];
    }
    __syncthreads();
    for (int idx = tid; idx < KCL * DM; idx += 256) {
        int i = idx / DM, d = idx - i * DM;
        float acc = 0.f;
#pragma unroll
        for (int j = 0; j < KCL; ++j) acc += Ss[i * 17 + j] * Ks[j * 388 + d];
        Qs[i * 388 + d] = acc;
    }
    __syncthreads();
    if (tid < 128) {
        int e = tid >> 4, i = tid & 15;
        float l = 0.f;
        for (int d4 = 0; d4 < DM / 4; ++d4) {
            float4 q = *(const float4*)&Qs[i * 388 + d4 * 4];
            float4 w = *(const float4*)&ewt[e * 388 + d4 * 4];
            l += q.x * w.x + q.y * w.y + q.z * w.z + q.w * w.w;
        }
        l += eb[e];
        float mx = l;
#pragma unroll
        for (int off = 8; off >= 1; off >>= 1) mx = fmaxf(mx, __shfl_xor(mx, off));
        float p = expf(l - mx);
        float sm = p;
#pragma unroll
        for (int off = 8; off >= 1; off >>= 1) sm += __shfl_xor(sm, off);
        float hh = p / sm;
        hws[i * 9 + e] = hh;
        float sd = hh;
#pragma unroll
        for (int off = 8; off >= 1; off >>= 1) sd += __shfl_xor(sd, off);
        if (i == 0) rds[e] = 1.0f / sqrtf(sd);
    }
    __syncthreads();
    if (tid < 64) {
        int e = tid >> 3, f = tid & 7;
        float gsum = 0.f;
#pragma unroll
        for (int k = 0; k < KCL; ++k) gsum += hws[k * 9 + e] * hws[k * 9 + f];
        Ls[e * 8 + f] = ((e == f) ? 1.0f : 0.0f) - rds[e] * gsum;
    }
    __syncthreads();
    for (int idx = tid; idx < KCL * DM; idx += 256) {
        int i = idx / DM, d = idx - i * DM;
        float acc = 0.f;
        if (i < NEXP) {
#pragma unroll
            for (int j = 0; j < NEXP; ++j) acc += Ls[i * 8 + j] * Qs[j * 388 + d];
        }
        c2[(size_t)b * KCL * DM + idx] = acc;
    }
}

// ---------------------------------------------------------------------------
// K6: normalize rows, sim = nc @ nc^T, OR (sim>0.9) into global mask
// ---------------------------------------------------------------------------
__global__ __launch_bounds__(256) void simmask_kernel(const float* __restrict__ c4,
                                                      int* __restrict__ mask) {
    __shared__ float Cs[KCL * 388];
    __shared__ float rns[KCL];
    const int b = blockIdx.x, tid = threadIdx.x;
    for (int idx = tid; idx < KCL * DM; idx += 256) {
        int i = idx / DM, d = idx - i * DM;
        Cs[i * 388 + d] = c4[(size_t)b * KCL * DM + idx];
    }
    __syncthreads();
    {
        int i = tid >> 4, s = tid & 15;
        float ss = 0.f;
        for (int t = 0; t < 24; ++t) { float v = Cs[i * 388 + s + 16 * t]; ss += v * v; }
#pragma unroll
        for (int off = 8; off >= 1; off >>= 1) ss += __shfl_xor(ss, off);
        if (s == 0) rns[i] = 1.0f / fmaxf(sqrtf(ss), 1e-12f);
    }
    __syncthreads();
    for (int idx = tid; idx < KCL * DM; idx += 256) {
        int i = idx / DM, d = idx - i * DM;
        Cs[i * 388 + d] *= rns[i];
    }
    __syncthreads();
    {
        int i = tid >> 4, j = tid & 15;
        if (j > i) {
            float dp = 0.f;
            for (int d = 0; d < DM; d += 4) {
                float4 a = *(const float4*)&Cs[i * 388 + d];
                float4 c = *(const float4*)&Cs[j * 388 + d];
                dp += a.x * c.x + a.y * c.y + a.z * c.z + a.w * c.w;
            }
            if (dp > 0.9f) atomicOr(&mask[i * KCL + j], 1);
        }
    }
}

// ---------------------------------------------------------------------------
// K7: sequential pairwise merge + mean + feedback gate -> c5
// ---------------------------------------------------------------------------
__global__ __launch_bounds__(256) void merge_fb_kernel(
        const float* __restrict__ c4, const int* __restrict__ mask,
        const float* __restrict__ fbw, const float* __restrict__ fbb,
        const float* __restrict__ fgw, const float* __restrict__ fgb,
        float* __restrict__ c5) {
    __shared__ int   mk[256];
    __shared__ float gs[DM];
    __shared__ float wred[3];
    __shared__ float gatev;
    const int b = blockIdx.x, tid = threadIdx.x;
    mk[tid] = mask[tid];
    const bool act = tid < 192;
    const int t = tid;
    float2 v[KCL];
    if (act) {
#pragma unroll
        for (int i = 0; i < KCL; ++i)
            v[i] = *(const float2*)(c4 + (size_t)b * KCL * DM + i * DM + 2 * t);
    }
    __syncthreads();
    if (act) {
#pragma unroll
        for (int i = 0; i < KCL; ++i)
#pragma unroll
            for (int j = i + 1; j < KCL; ++j)
                if (mk[i * KCL + j]) {
                    float mx = 0.5f * (v[i].x + v[j].x);
                    float my = 0.5f * (v[i].y + v[j].y);
                    v[i].x = mx; v[i].y = my; v[j].x = mx; v[j].y = my;
                }
    }
    float2 gv = {0.f, 0.f};
    if (act) {
#pragma unroll
        for (int i = 0; i < KCL; ++i) { gv.x += v[i].x; gv.y += v[i].y; }
        gv.x *= 0.0625f; gv.y *= 0.0625f;
        gs[2 * t] = gv.x; gs[2 * t + 1] = gv.y;
    }
    float pg = act ? (gv.x * fgw[2 * t] + gv.y * fgw[2 * t + 1]) : 0.f;
#pragma unroll
    for (int off = 32; off >= 1; off >>= 1) pg += __shfl_xor(pg, off);
    if (act && (tid & 63) == 0) wred[tid >> 6] = pg;
    __syncthreads();
    if (tid == 0) {
        float d = wred[0] + wred[1] + wred[2] + fgb[0];
        gatev = 1.0f / (1.0f + expf(-d));
    }
    __syncthreads();
    if (act) {
        float fx = fbb[2 * t], fy = fbb[2 * t + 1];
        for (int j = 0; j < DM; ++j) {
            float gj = gs[j];
            const float2 w = *(const float2*)(fbw + (size_t)j * DM + 2 * t);
            fx += gj * w.x; fy += gj * w.y;
        }
        float gt = gatev;
#pragma unroll
        for (int i = 0; i < KCL; ++i) {
            float2 o = {v[i].x + fx * gt, v[i].y + fy * gt};
            *(float2*)(c5 + (size_t)b * KCL * DM + i * DM + 2 * t) = o;
        }
    }
}

// ---------------------------------------------------------------------------
// K8: classifier, split-K with fp32 atomics. out pre-initialized with cb.
// ---------------------------------------------------------------------------
__global__ __launch_bounds__(256) void cls_kernel(const float* __restrict__ A,
                                                  const float* __restrict__ Wt,
                                                  float* __restrict__ out) {
    __shared__ float As[32 * 32];
    __shared__ float Ws[32 * 128];
    const int n0 = blockIdx.x * 128;
    const int m0 = blockIdx.y * 32;
    const int k0 = blockIdx.z * 768;
    const int tid = threadIdx.x;
    const int rg = tid >> 5, cg = tid & 31;
    const int arow = tid >> 3, akg = tid & 7;
    float acc[4][4];
#pragma unroll
    for (int r = 0; r < 4; ++r)
#pragma unroll
        for (int j = 0; j < 4; ++j) acc[r][j] = 0.f;

    for (int kc = k0; kc < k0 + 768; kc += 32) {
        float4 av = *(const float4*)(A + (size_t)(m0 + arow) * (KCL * DM) + kc + akg * 4);
        As[(akg * 4 + 0) * 32 + arow] = av.x;
        As[(akg * 4 + 1) * 32 + arow] = av.y;
        As[(akg * 4 + 2) * 32 + arow] = av.z;
        As[(akg * 4 + 3) * 32 + arow] = av.w;
#pragma unroll
        for (int ti = 0; ti < 4; ++ti) {
            int s = tid + ti * 256;
            int kk = s >> 5, c4i = s & 31;
            int col = n0 + c4i * 4;
            float4 wv = make_float4(0.f, 0.f, 0.f, 0.f);
            if (col < NCLS) wv = *(const float4*)(Wt + (size_t)(kc + kk) * NCLS + col);
            *(float4*)&Ws[kk * 128 + c4i * 4] = wv;
        }
        __syncthreads();
#pragma unroll 16
        for (int kk = 0; kk < 32; ++kk) {
            float4 a = *(const float4*)&As[kk * 32 + rg * 4];
            float4 w = *(const float4*)&Ws[kk * 128 + cg * 4];
            float ar[4] = {a.x, a.y, a.z, a.w};
            float wr[4] = {w.x, w.y, w.z, w.w};
#pragma unroll
            for (int r = 0; r < 4; ++r)
#pragma unroll
                for (int j = 0; j < 4; ++j) acc[r][j] += ar[r] * wr[j];
        }
        __syncthreads();
    }
    int col = n0 + cg * 4;
    if (col < NCLS) {
#pragma unroll
        for (int r = 0; r < 4; ++r) {
            int row = m0 + rg * 4 + r;
#pragma unroll
            for (int j = 0; j < 4; ++j)
                atomicAdd(&out[(size_t)row * NCLS + col + j], acc[r][j]);
        }
    }
}

// ---------------------------------------------------------------------------
extern "C" void kernel_launch(void* const* d_in, const int* in_sizes, int n_in,
                              void* d_out, int out_size, void* d_ws, size_t ws_size,
                              hipStream_t stream) {
    const float* x   = (const float*)d_in[0];
    const float* pw  = (const float*)d_in[1];
    const float* pb  = (const float*)d_in[2];
    const float* lng = (const float*)d_in[3];
    const float* lnb = (const float*)d_in[4];
    const float* pos = (const float*)d_in[5];
    const float* qw  = (const float*)d_in[6];
    const float* qb  = (const float*)d_in[7];
    const float* kw  = (const float*)d_in[8];
    const float* kb  = (const float*)d_in[9];
    const float* vw  = (const float*)d_in[10];
    const float* vb  = (const float*)d_in[11];
    const float* ew  = (const float*)d_in[12];
    const float* eb  = (const float*)d_in[13];
    const float* nw  = (const float*)d_in[14];
    const float* nb  = (const float*)d_in[15];
    const float* m1w = (const float*)d_in[16];
    const float* m1b = (const float*)d_in[17];
    const float* m2w = (const float*)d_in[18];
    const float* m2b = (const float*)d_in[19];
    const float* fbw = (const float*)d_in[20];
    const float* fbb = (const float*)d_in[21];
    const float* fgw = (const float*)d_in[22];
    const float* fgb = (const float*)d_in[23];
    const float* cw  = (const float*)d_in[24];
    const float* cb  = (const float*)d_in[25];
    float* out = (float*)d_out;
    float* ws  = (float*)d_ws;

    // workspace layout (floats)
    float* pn_   = ws;                    // 128*196*384 = 9,633,792
    float* pnsq_ = ws + 9633792;          // 25,088
    float* c0_   = ws + 9658880;          // 786,432 (clusters0; later c5)
    float* Q_    = ws + 10445312;         // 786,432 (later c3)
    float* K_    = ws + 11231744;         // 786,432 (later h)
    float* V_    = ws + 12018176;         // 786,432 (later c4)
    float* c2_   = ws + 12804608;         // 786,432
    int*   mask_ = (int*)(ws + 13591040); // 256 ints
    float* c3_ = Q_;
    float* h_  = K_;
    float* c4_ = V_;
    float* c5_ = c0_;

    init_kernel<<<501, 256, 0, stream>>>(cb, out, mask_);
    patch_ln_kernel<<<392, 256, 0, stream>>>(x, pw, pb, lng, lnb, pn_, pnsq_);
    kmeans_kernel<<<NBATCH, 512, 0, stream>>>(pn_, pnsq_, pos, c0_);
    gemm_qkv_kernel<<<dim3(3, 64), 256, 0, stream>>>(c0_, qw, kw, vw, qb, kb, vb,
                                                     Q_, K_, V_);
    attn_spectral_kernel<<<NBATCH, 256, 0, stream>>>(Q_, K_, V_, ew, eb, c2_);
    gemm_kernel<0><<<dim3(3, 64), 256, 0, stream>>>(c2_, nw, nb, c3_, 2048, DM, DM);
    gemm_kernel<1><<<dim3(3, 64), 256, 0, stream>>>(c3_, m1w, m1b, h_, 2048, DM, DM);
    gemm_kernel<0><<<dim3(3, 64), 256, 0, stream>>>(h_, m2w, m2b, c4_, 2048, DM, DM);
    simmask_kernel<<<NBATCH, 256, 0, stream>>>(c4_, mask_);
    merge_fb_kernel<<<NBATCH, 256, 0, stream>>>(c4_, mask_, fbw, fbb, fgw, fgb, c5_);
    cls_kernel<<<dim3(8, 4, 8), 256, 0, stream>>>(c5_, cw, out);
}